// Round 5
// baseline (396.073 us; speedup 1.0000x reference)
//
#include <hip/hip_runtime.h>

#define NN 8192

typedef __bf16 bf16x8 __attribute__((ext_vector_type(8)));
typedef float f32x4 __attribute__((ext_vector_type(4)));
typedef unsigned short u16x8 __attribute__((ext_vector_type(8)));
typedef unsigned int u32x4 __attribute__((ext_vector_type(4)));

__device__ __forceinline__ unsigned short f2bf(float f) {
  unsigned int u = __builtin_bit_cast(unsigned int, f);
  u += 0x7FFFu + ((u >> 16) & 1u);   // RNE
  return (unsigned short)(u >> 16);
}
__device__ __forceinline__ float bf2f(unsigned short b) {
  unsigned int u = ((unsigned int)b) << 16;
  return __builtin_bit_cast(float, u);
}

// byte (8 adjacency bits) -> 8 bf16 {0.0, 1.0} in-register.
// Per u32 pair: (b&1)*0x3F80 gives low half, (b&2)*0x1FC00000 == bit1*0x3F800000.
__device__ __forceinline__ bf16x8 expand8(unsigned int b) {
  const unsigned int s2 = b >> 2, s4 = b >> 4, s6 = b >> 6;
  u32x4 r;
  r[0] = (b  & 1u) * 0x3F80u + (b  & 2u) * 0x1FC00000u;
  r[1] = (s2 & 1u) * 0x3F80u + (s2 & 2u) * 0x1FC00000u;
  r[2] = (s4 & 1u) * 0x3F80u + (s4 & 2u) * 0x1FC00000u;
  r[3] = (s6 & 1u) * 0x3F80u + (s6 & 2u) * 0x1FC00000u;
  return __builtin_bit_cast(bf16x8, r);
}

// ---------------------------------------------------------------------------
// K0: pack.  Streams adj (268 MB) ONCE at HBM BW; emits
//   mask[row][c] : uint64, bit b = (adj[row][c*64+b] > 0)        (8 MB)
//   degp[half][row] : popcount of row half                        (64 KB)
// ---------------------------------------------------------------------------
__global__ __launch_bounds__(256) void pack_kernel(
    const int* __restrict__ adj, unsigned long long* __restrict__ mask,
    float* __restrict__ degp) {
  __shared__ unsigned long long sm[4][64];
  const int lane = threadIdx.x & 63;
  const int wv = threadIdx.x >> 6;
  const int wid = (blockIdx.x << 2) + wv;
  const int row = wid >> 1, half = wid & 1;
  const int* src = adj + (size_t)row * NN + half * 4096 + lane;
  int deg = 0;
#pragma unroll
  for (int c = 0; c < 64; ++c) {
    int v = src[c * 64];
    unsigned long long m = __ballot(v > 0);
    if (lane == 0) sm[wv][c] = m;
    deg += (int)__popcll(m);
  }
  __syncthreads();
  mask[(size_t)row * 128 + half * 64 + lane] = sm[wv][lane];
  if (lane == 0) degp[half * NN + row] = (float)deg;
}

// ---------------------------------------------------------------------------
// K1: prep.  Per block: one batch b, 64 nodes.  Computes
//   Yt[(b*64+fo)][j] = bf16( x[b,j,:] @ W_neigh[:,fo] )   (transposed, LINEAR)
//   Sbf[b,j,fo]      = bf16( x[b,j,:] @ W_self [:,fo] + b_self[fo] )  -> ws
// ---------------------------------------------------------------------------
__global__ __launch_bounds__(256) void prep_kernel(
    const float* __restrict__ x, const float* __restrict__ Wself,
    const float* __restrict__ bself, const float* __restrict__ Wneigh,
    unsigned short* __restrict__ Yt, unsigned short* __restrict__ Sout) {
  __shared__ __align__(16) unsigned short xa[64 * 64];    // [j][k] swizzled
  __shared__ __align__(16) unsigned short bm[128 * 64];   // [n][k]; n<64: Wneigh, n>=64: Wself
  const int t = threadIdx.x;
  const int b = blockIdx.x >> 7;
  const int j0 = (blockIdx.x & 127) << 6;

  {
    const float* Wsel = (t < 128) ? Wneigh : Wself;
    const int tt = t & 127;
    const int k = tt >> 1;
    const int c0 = (tt & 1) << 5;
    const int nbase = (t < 128) ? 0 : 64;
    const float4* src = (const float4*)(Wsel + k * 64 + c0);
#pragma unroll
    for (int q = 0; q < 8; ++q) {
      float4 v = src[q];
      int n0 = nbase + c0 + q * 4;
      int n;
      n = n0 + 0; bm[n * 64 + (k ^ ((n & 7) << 3))] = f2bf(v.x);
      n = n0 + 1; bm[n * 64 + (k ^ ((n & 7) << 3))] = f2bf(v.y);
      n = n0 + 2; bm[n * 64 + (k ^ ((n & 7) << 3))] = f2bf(v.z);
      n = n0 + 3; bm[n * 64 + (k ^ ((n & 7) << 3))] = f2bf(v.w);
    }
  }
  {
    const int j = t >> 2, q = t & 3;
    const float* xrow = x + ((size_t)b * NN + j0 + j) * 64 + q * 16;
    float4 v0 = *(const float4*)(xrow + 0);
    float4 v1 = *(const float4*)(xrow + 4);
    float4 v2 = *(const float4*)(xrow + 8);
    float4 v3 = *(const float4*)(xrow + 12);
    u16x8 p0, p1;
    p0[0] = f2bf(v0.x); p0[1] = f2bf(v0.y); p0[2] = f2bf(v0.z); p0[3] = f2bf(v0.w);
    p0[4] = f2bf(v1.x); p0[5] = f2bf(v1.y); p0[6] = f2bf(v1.z); p0[7] = f2bf(v1.w);
    p1[0] = f2bf(v2.x); p1[1] = f2bf(v2.y); p1[2] = f2bf(v2.z); p1[3] = f2bf(v2.w);
    p1[4] = f2bf(v3.x); p1[5] = f2bf(v3.y); p1[6] = f2bf(v3.z); p1[7] = f2bf(v3.w);
    const int base = q * 16;
    const int sw = (j & 7) << 3;
    *(u16x8*)&xa[j * 64 + (base ^ sw)] = p0;
    *(u16x8*)&xa[j * 64 + ((base + 8) ^ sw)] = p1;
  }
  __syncthreads();

  const int lane = t & 63, w = t >> 6;
  const int rl = lane & 15, hi = lane >> 4;
  f32x4 acc[8];
#pragma unroll
  for (int i = 0; i < 8; ++i) acc[i] = (f32x4){0.f, 0.f, 0.f, 0.f};

#pragma unroll
  for (int ks = 0; ks < 2; ++ks) {
    const int r = w * 16 + rl;
    const int kel = ks * 32 + hi * 8;
    bf16x8 af = __builtin_bit_cast(bf16x8, *(u16x8*)&xa[r * 64 + (kel ^ ((r & 7) << 3))]);
#pragma unroll
    for (int nf = 0; nf < 8; ++nf) {
      const int n = nf * 16 + rl;
      bf16x8 bv = __builtin_bit_cast(bf16x8, *(u16x8*)&bm[n * 64 + (kel ^ ((n & 7) << 3))]);
      acc[nf] = __builtin_amdgcn_mfma_f32_16x16x32_bf16(af, bv, acc[nf], 0, 0, 0);
    }
  }
#pragma unroll
  for (int nf = 0; nf < 8; ++nf) {
    if (nf < 4) {
      const int n = nf * 16 + rl;
      unsigned short* yrow = Yt + (size_t)(b * 64 + n) * NN + j0;
#pragma unroll
      for (int r = 0; r < 4; ++r) {
        const int jj = w * 16 + hi * 4 + r;
        yrow[jj] = f2bf(acc[nf][r]);            // LINEAR (direct-load gemm)
      }
    } else {
      const int fo = (nf - 4) * 16 + rl;
      const float bsv = bself[fo];
#pragma unroll
      for (int r = 0; r < 4; ++r) {
        const int jj = w * 16 + hi * 4 + r;
        Sout[((size_t)b * NN + j0 + jj) * 64 + fo] = f2bf(acc[nf][r] + bsv);
      }
    }
  }
}

// ---------------------------------------------------------------------------
// K2: big GEMM  C[i][n] = sum_j bit(i,j) * Yt[n][j],  n = b*64+fo.
// BARRIER-FREE, LDS-FREE: each wave owns a 32x128 output tile and free-runs.
//   - B (Y) fragments loaded DIRECTLY L2->VGPR (global_load_dwordx4): the
//     16x16x32 B-frag is 16B-contiguous per lane in Yt row-major layout.
//   - A fragments expanded in-register from the 8 MB bitmask.
//   - Register double-buffer (sets A/B) over a 2x-unrolled K-loop; no
//     __syncthreads, no LDS, waves hide each other's L2 latency (2/SIMD).
// BM=128 (4 waves x 32 rows), BN=128, ksp x2 -> grid 512.
// XCD decode: nid = (ksp*4+nb)*64+mb -> each XCD owns one 1 MB Yt slice.
// C bf16 partials (2 ksp planes) land in d_out (combined by epiA).
// ---------------------------------------------------------------------------
__global__ __launch_bounds__(256, 2) void gemm_kernel(
    const unsigned long long* __restrict__ mask,
    const unsigned short* __restrict__ Yt, unsigned short* __restrict__ Cp) {
  const int tid = threadIdx.x;
  const int lane = tid & 63, w = tid >> 6;
  const int nid = ((blockIdx.x & 7) << 6) + (blockIdx.x >> 3);
  const int mb  = nid & 63;
  const int nb  = (nid >> 6) & 3;
  const int ksp = nid >> 8;
  const int i0    = mb << 7;      // 128 rows
  const int kbase = ksp << 12;    // 4096 k-elems
  const int ncol0 = nb << 7;      // 128 cols

  const int rl = lane & 15, hi = lane >> 4;
  const int hi8 = hi << 3;

  // mask rows for this wave: mf=0 -> i0 + w*32 + rl, mf=1 -> +16
  const unsigned long long* mp0 = mask + (size_t)(i0 + (w << 5) + rl) * 128 + (ksp << 6);
  const unsigned long long* mp1 = mp0 + 16 * 128;
  // Y base for (nf, ks, t): col = ncol0 + nf*16 + rl, elem = kbase + t*64 + ks*32 + hi8
  const unsigned short* yb = Yt + (size_t)(ncol0 + rl) * NN + kbase + hi8;

  f32x4 acc[2][8];
#pragma unroll
  for (int mf = 0; mf < 2; ++mf)
#pragma unroll
    for (int nf = 0; nf < 8; ++nf) acc[mf][nf] = (f32x4){0.f, 0.f, 0.f, 0.f};

  u16x8 YA[16], YB[16];
  unsigned long long MA[2], MB[2];

#define LOADSET(Y, M, t)                                                      \
  {                                                                           \
    _Pragma("unroll")                                                         \
    for (int nf_ = 0; nf_ < 8; ++nf_) {                                       \
      const unsigned short* p_ = yb + (size_t)nf_ * (16 * NN) + (t) * 64;     \
      Y[nf_ * 2 + 0] = *(const u16x8*)(p_);                                   \
      Y[nf_ * 2 + 1] = *(const u16x8*)(p_ + 32);                              \
    }                                                                         \
    M[0] = mp0[(t)];                                                          \
    M[1] = mp1[(t)];                                                          \
  }

#define COMPSET(Y, M)                                                         \
  {                                                                           \
    _Pragma("unroll")                                                         \
    for (int mf_ = 0; mf_ < 2; ++mf_) {                                       \
      const unsigned long long mv_ = M[mf_];                                  \
      _Pragma("unroll")                                                       \
      for (int ks_ = 0; ks_ < 2; ++ks_) {                                     \
        const unsigned int h_ = (unsigned int)(mv_ >> (ks_ * 32));            \
        const bf16x8 af_ = expand8(h_ >> hi8);                                \
        _Pragma("unroll")                                                     \
        for (int nf_ = 0; nf_ < 8; ++nf_)                                     \
          acc[mf_][nf_] = __builtin_amdgcn_mfma_f32_16x16x32_bf16(            \
              af_, __builtin_bit_cast(bf16x8, Y[nf_ * 2 + ks_]),              \
              acc[mf_][nf_], 0, 0, 0);                                        \
      }                                                                       \
    }                                                                         \
  }

  LOADSET(YA, MA, 0);
  for (int t2 = 0; t2 < 64; t2 += 2) {
    LOADSET(YB, MB, t2 + 1);
    COMPSET(YA, MA);
    LOADSET(YA, MA, (t2 + 2) & 63);   // wraps harmlessly on last iter
    COMPSET(YB, MB);
  }
#undef LOADSET
#undef COMPSET

  // C partial write (bf16 plane ksp in d_out)
#pragma unroll
  for (int mf = 0; mf < 2; ++mf)
#pragma unroll
    for (int nf = 0; nf < 8; ++nf) {
      const int col = ncol0 + nf * 16 + rl;
#pragma unroll
      for (int r = 0; r < 4; ++r) {
        const int i = i0 + (w << 5) + mf * 16 + hi * 4 + r;
        Cp[((size_t)ksp * NN + i) * 512 + col] = f2bf(acc[mf][nf][r]);
      }
    }
}

// ---------------------------------------------------------------------------
// K3: epiA.  F[i][col] = deg>0 ? (Cp0+Cp1)/deg + b_neigh[fo] : 0   (bf16)
// Reads Cp planes from d_out, writes F into ws (reusing the mask region).
// ---------------------------------------------------------------------------
__global__ __launch_bounds__(256) void epiA_kernel(
    const unsigned short* __restrict__ Cp, const float* __restrict__ degp,
    const float* __restrict__ bneigh, unsigned short* __restrict__ F) {
  const int idx = (blockIdx.x << 8) + threadIdx.x;   // 524288 threads
  const size_t cidx = (size_t)idx * 8;
  const int i = (int)(cidx >> 9);
  const int fo0 = (int)(cidx & 511) & 63;
  const float deg = degp[i] + degp[NN + i];
  const bool has = deg > 0.5f;
  const float r = has ? 1.0f / deg : 0.0f;
  u16x8 c0 = *(const u16x8*)&Cp[cidx];
  u16x8 c1 = *(const u16x8*)&Cp[(size_t)NN * 512 + cidx];
  float4 bn0 = *(const float4*)&bneigh[fo0];
  float4 bn1 = *(const float4*)&bneigh[fo0 + 4];
  u16x8 f;
#pragma unroll
  for (int j = 0; j < 8; ++j) {
    const float bn = (j < 4) ? ((const float*)&bn0)[j] : ((const float*)&bn1)[j - 4];
    const float v = (bf2f(c0[j]) + bf2f(c1[j])) * r + bn;
    f[j] = has ? f2bf(v) : (unsigned short)0;
  }
  *(u16x8*)&F[cidx] = f;
}

// ---------------------------------------------------------------------------
// K4: epiB.  One wave per (b,i); lane = fo.
// v = relu(S + F); LayerNorm over fo; write f32 to d_out.
// ---------------------------------------------------------------------------
__global__ __launch_bounds__(256) void epiB_kernel(
    const unsigned short* __restrict__ F, const unsigned short* __restrict__ Sbf,
    const float* __restrict__ gamma, const float* __restrict__ beta,
    float* __restrict__ out) {
  const int lane = threadIdx.x & 63;
  const int wid = (blockIdx.x << 2) + (threadIdx.x >> 6);
  const int b = wid >> 13;
  const int i = wid & (NN - 1);
  const float sv = bf2f(Sbf[((size_t)b * NN + i) * 64 + lane]);
  const float fv = bf2f(F[(size_t)i * 512 + b * 64 + lane]);
  float v = fmaxf(sv + fv, 0.0f);
  float s1 = v, s2 = v * v;
#pragma unroll
  for (int m = 1; m < 64; m <<= 1) {
    s1 += __shfl_xor(s1, m);
    s2 += __shfl_xor(s2, m);
  }
  const float mu = s1 * 0.015625f;
  const float var = s2 * 0.015625f - mu * mu;
  const float o = (v - mu) * rsqrtf(var + 1e-5f) * gamma[lane] + beta[lane];
  out[((size_t)b * NN + i) * 64 + lane] = o;
}

extern "C" void kernel_launch(void* const* d_in, const int* in_sizes, int n_in,
                              void* d_out, int out_size, void* d_ws, size_t ws_size,
                              hipStream_t stream) {
  (void)in_sizes; (void)n_in; (void)out_size; (void)ws_size;
  const float* x      = (const float*)d_in[0];
  const int*   adj    = (const int*)d_in[1];
  const float* Wself  = (const float*)d_in[2];
  const float* bself  = (const float*)d_in[3];
  const float* Wneigh = (const float*)d_in[4];
  const float* bneigh = (const float*)d_in[5];
  const float* gamma  = (const float*)d_in[6];
  const float* beta   = (const float*)d_in[7];
  char* ws = (char*)d_ws;
  // ws layout (25,231,360 B total):
  unsigned short*     Yt   = (unsigned short*)ws;                    //  8 MB
  unsigned long long* mask = (unsigned long long*)(ws + 8388608);    //  8 MB
  unsigned short*     Sbf  = (unsigned short*)(ws + 16777216);       //  8 MB
  float*              degp = (float*)(ws + 25165824);                // 64 KB
  unsigned short*     F    = (unsigned short*)(ws + 8388608);        // alias mask (dead after gemm)
  unsigned short*     Cp   = (unsigned short*)d_out;                 // 2 bf16 planes in d_out
  float*              out  = (float*)d_out;

  pack_kernel<<<dim3(4096), dim3(256), 0, stream>>>(adj, mask, degp);
  prep_kernel<<<dim3(1024), dim3(256), 0, stream>>>(x, Wself, bself, Wneigh, Yt, Sbf);
  gemm_kernel<<<dim3(512), dim3(256), 0, stream>>>(mask, Yt, Cp);
  epiA_kernel<<<dim3(2048), dim3(256), 0, stream>>>(Cp, degp, bneigh, F);
  epiB_kernel<<<dim3(16384), dim3(256), 0, stream>>>(F, Sbf, gamma, beta, out);
}

// Round 6
// 313.821 us; speedup vs baseline: 1.2621x; 1.2621x over previous
//
#include <hip/hip_runtime.h>

#define NN 8192

typedef __bf16 bf16x8 __attribute__((ext_vector_type(8)));
typedef float f32x4 __attribute__((ext_vector_type(4)));
typedef unsigned short u16x8 __attribute__((ext_vector_type(8)));
typedef unsigned int u32x4 __attribute__((ext_vector_type(4)));

#define GLOBAL_AS __attribute__((address_space(1)))
#define LDS_AS __attribute__((address_space(3)))

__device__ __forceinline__ unsigned short f2bf(float f) {
  unsigned int u = __builtin_bit_cast(unsigned int, f);
  u += 0x7FFFu + ((u >> 16) & 1u);   // RNE
  return (unsigned short)(u >> 16);
}
__device__ __forceinline__ float bf2f(unsigned short b) {
  unsigned int u = ((unsigned int)b) << 16;
  return __builtin_bit_cast(float, u);
}

// byte (8 adjacency bits) -> 8 bf16 {0.0, 1.0} in-register.
__device__ __forceinline__ bf16x8 expand8(unsigned int b) {
  const unsigned int s2 = b >> 2, s4 = b >> 4, s6 = b >> 6;
  u32x4 r;
  r[0] = (b  & 1u) * 0x3F80u + (b  & 2u) * 0x1FC00000u;
  r[1] = (s2 & 1u) * 0x3F80u + (s2 & 2u) * 0x1FC00000u;
  r[2] = (s4 & 1u) * 0x3F80u + (s4 & 2u) * 0x1FC00000u;
  r[3] = (s6 & 1u) * 0x3F80u + (s6 & 2u) * 0x1FC00000u;
  return __builtin_bit_cast(bf16x8, r);
}

// ---------------------------------------------------------------------------
// K0: pack.  Streams adj (268 MB) ONCE at HBM BW; emits
//   mask[row][c] : uint64, bit b = (adj[row][c*64+b] > 0)        (8 MB)
//   degp[half][row] : popcount of row half                        (64 KB)
// ---------------------------------------------------------------------------
__global__ __launch_bounds__(256) void pack_kernel(
    const int* __restrict__ adj, unsigned long long* __restrict__ mask,
    float* __restrict__ degp) {
  __shared__ unsigned long long sm[4][64];
  const int lane = threadIdx.x & 63;
  const int wv = threadIdx.x >> 6;
  const int wid = (blockIdx.x << 2) + wv;
  const int row = wid >> 1, half = wid & 1;
  const int* src = adj + (size_t)row * NN + half * 4096 + lane;
  int deg = 0;
#pragma unroll
  for (int c = 0; c < 64; ++c) {
    int v = src[c * 64];
    unsigned long long m = __ballot(v > 0);
    if (lane == 0) sm[wv][c] = m;
    deg += (int)__popcll(m);
  }
  __syncthreads();
  mask[(size_t)row * 128 + half * 64 + lane] = sm[wv][lane];
  if (lane == 0) degp[half * NN + row] = (float)deg;
}

// ---------------------------------------------------------------------------
// K1: prep.  Per block: one batch b, 64 nodes.  Computes
//   Yt[(b*64+fo)][j] = bf16( x[b,j,:] @ W_neigh[:,fo] )   (transposed, LINEAR)
//   Sbf[b,j,fo]      = bf16( x[b,j,:] @ W_self [:,fo] + b_self[fo] )  -> ws
// ---------------------------------------------------------------------------
__global__ __launch_bounds__(256) void prep_kernel(
    const float* __restrict__ x, const float* __restrict__ Wself,
    const float* __restrict__ bself, const float* __restrict__ Wneigh,
    unsigned short* __restrict__ Yt, unsigned short* __restrict__ Sout) {
  __shared__ __align__(16) unsigned short xa[64 * 64];    // [j][k] swizzled
  __shared__ __align__(16) unsigned short bm[128 * 64];   // [n][k]; n<64: Wneigh, n>=64: Wself
  const int t = threadIdx.x;
  const int b = blockIdx.x >> 7;
  const int j0 = (blockIdx.x & 127) << 6;

  {
    const float* Wsel = (t < 128) ? Wneigh : Wself;
    const int tt = t & 127;
    const int k = tt >> 1;
    const int c0 = (tt & 1) << 5;
    const int nbase = (t < 128) ? 0 : 64;
    const float4* src = (const float4*)(Wsel + k * 64 + c0);
#pragma unroll
    for (int q = 0; q < 8; ++q) {
      float4 v = src[q];
      int n0 = nbase + c0 + q * 4;
      int n;
      n = n0 + 0; bm[n * 64 + (k ^ ((n & 7) << 3))] = f2bf(v.x);
      n = n0 + 1; bm[n * 64 + (k ^ ((n & 7) << 3))] = f2bf(v.y);
      n = n0 + 2; bm[n * 64 + (k ^ ((n & 7) << 3))] = f2bf(v.z);
      n = n0 + 3; bm[n * 64 + (k ^ ((n & 7) << 3))] = f2bf(v.w);
    }
  }
  {
    const int j = t >> 2, q = t & 3;
    const float* xrow = x + ((size_t)b * NN + j0 + j) * 64 + q * 16;
    float4 v0 = *(const float4*)(xrow + 0);
    float4 v1 = *(const float4*)(xrow + 4);
    float4 v2 = *(const float4*)(xrow + 8);
    float4 v3 = *(const float4*)(xrow + 12);
    u16x8 p0, p1;
    p0[0] = f2bf(v0.x); p0[1] = f2bf(v0.y); p0[2] = f2bf(v0.z); p0[3] = f2bf(v0.w);
    p0[4] = f2bf(v1.x); p0[5] = f2bf(v1.y); p0[6] = f2bf(v1.z); p0[7] = f2bf(v1.w);
    p1[0] = f2bf(v2.x); p1[1] = f2bf(v2.y); p1[2] = f2bf(v2.z); p1[3] = f2bf(v2.w);
    p1[4] = f2bf(v3.x); p1[5] = f2bf(v3.y); p1[6] = f2bf(v3.z); p1[7] = f2bf(v3.w);
    const int base = q * 16;
    const int sw = (j & 7) << 3;
    *(u16x8*)&xa[j * 64 + (base ^ sw)] = p0;
    *(u16x8*)&xa[j * 64 + ((base + 8) ^ sw)] = p1;
  }
  __syncthreads();

  const int lane = t & 63, w = t >> 6;
  const int rl = lane & 15, hi = lane >> 4;
  f32x4 acc[8];
#pragma unroll
  for (int i = 0; i < 8; ++i) acc[i] = (f32x4){0.f, 0.f, 0.f, 0.f};

#pragma unroll
  for (int ks = 0; ks < 2; ++ks) {
    const int r = w * 16 + rl;
    const int kel = ks * 32 + hi * 8;
    bf16x8 af = __builtin_bit_cast(bf16x8, *(u16x8*)&xa[r * 64 + (kel ^ ((r & 7) << 3))]);
#pragma unroll
    for (int nf = 0; nf < 8; ++nf) {
      const int n = nf * 16 + rl;
      bf16x8 bv = __builtin_bit_cast(bf16x8, *(u16x8*)&bm[n * 64 + (kel ^ ((n & 7) << 3))]);
      acc[nf] = __builtin_amdgcn_mfma_f32_16x16x32_bf16(af, bv, acc[nf], 0, 0, 0);
    }
  }
#pragma unroll
  for (int nf = 0; nf < 8; ++nf) {
    if (nf < 4) {
      const int n = nf * 16 + rl;
      unsigned short* yrow = Yt + (size_t)(b * 64 + n) * NN + j0;
#pragma unroll
      for (int r = 0; r < 4; ++r) {
        const int jj = w * 16 + hi * 4 + r;
        yrow[jj] = f2bf(acc[nf][r]);            // LINEAR
      }
    } else {
      const int fo = (nf - 4) * 16 + rl;
      const float bsv = bself[fo];
#pragma unroll
      for (int r = 0; r < 4; ++r) {
        const int jj = w * 16 + hi * 4 + r;
        Sout[((size_t)b * NN + j0 + jj) * 64 + fo] = f2bf(acc[nf][r] + bsv);
      }
    }
  }
}

// ---------------------------------------------------------------------------
// K2: big GEMM  C[i][n] = sum_j bit(i,j) * Yt[n][j],  n = b*64+fo.
// Traffic-minimal shape: BM=512, BN=64, ksp=2 -> 256 blocks (1/CU).
// Total staged bytes: Y 128 MB + mask 64 MB + C 16 MB (vs 1-2 GB before).
// 8 waves (4 row-groups x 2 col-groups); wave = 128 rows x 32 cols.
// Y: quad-buffered 8KB step-tiles in LDS (1 global_load_lds/wave/step,
//    source pre-swizzled chunk^=(col&7) to spread ds_read banks).
// A: bitmask u64 per row, depth-1 register prefetch, VALU expand -> bf16.
// One s_barrier + one counted s_waitcnt vmcnt(9) per K-step; iteration
// groups pinned by asm memory clobbers, so Y(t) always has >=18 newer
// VMEM ops at the wait -> guaranteed drained without vmcnt(0).
// C bf16 partials (2 ksp planes) land in d_out (combined by epiA).
// ---------------------------------------------------------------------------
__global__ __launch_bounds__(512, 1) void gemm_kernel(
    const unsigned long long* __restrict__ mask,
    const unsigned short* __restrict__ Yt, unsigned short* __restrict__ Cp) {
  __shared__ __align__(16) unsigned short yL[4][64 * 64];   // 4 x 8 KB
  const int tid = threadIdx.x;
  const int lane = tid & 63;
  const int w = tid >> 6;            // 0..7
  const int wr = w >> 1;             // row-group: 128 rows each
  const int wc = w & 1;              // col-group: 32 cols each
  // XCD grouping: nid = (bid&7)*32 + bid>>3; q = (ksp,nb), mb = nid&15
  const int nid = ((blockIdx.x & 7) << 5) + (blockIdx.x >> 3);
  const int q = nid >> 4, mb = nid & 15;
  const int ksp = q >> 3, nb = q & 7;
  const int i0 = mb << 9;            // 512 rows
  const int kbase = ksp << 12;       // K half
  const int ncol0 = nb << 6;         // 64 cols
  const int rl = lane & 15, hi4 = lane >> 4;
  const int hs = hi4 << 3;

  // Y staging source (pre-swizzled): lane -> col cl, chunk (lane&7)^(cl&7)
  const int cl_st = (w << 3) + (lane >> 3);
  const unsigned short* ysrc = Yt + (size_t)(ncol0 + cl_st) * NN + kbase
                               + (((lane & 7) ^ (cl_st & 7)) << 3);
  // mask row pointers, one per 16-row fragment
  const unsigned long long* mp[8];
#pragma unroll
  for (int mf = 0; mf < 8; ++mf)
    mp[mf] = mask + (size_t)(i0 + (wr << 7) + mf * 16 + rl) * 128 + (ksp << 6);

  // B-read LDS offsets (elems) per [nf][ks], swizzled
  int boff[2][2];
#pragma unroll
  for (int nf = 0; nf < 2; ++nf)
#pragma unroll
    for (int ks = 0; ks < 2; ++ks) {
      const int c = (wc << 5) + (nf << 4) + rl;
      boff[nf][ks] = (c << 6) + ((((ks << 2) + hi4) ^ (c & 7)) << 3);
    }

  f32x4 acc[8][2];
#pragma unroll
  for (int mf = 0; mf < 8; ++mf) {
    acc[mf][0] = (f32x4){0.f, 0.f, 0.f, 0.f};
    acc[mf][1] = (f32x4){0.f, 0.f, 0.f, 0.f};
  }

  unsigned long long Ma[8], Mb[8];

#define BARRIER  __builtin_amdgcn_s_barrier()
#define FENCE    __builtin_amdgcn_sched_barrier(0)
#define WAIT_VM9 asm volatile("s_waitcnt vmcnt(9)" ::: "memory")

#define STAGE(buf, t)                                                         \
  __builtin_amdgcn_global_load_lds(                                           \
      (GLOBAL_AS void*)const_cast<unsigned short*>(ysrc + (size_t)(t) * 64),  \
      (LDS_AS void*)&yL[buf][w << 9], 16, 0, 0)

#define LOADM(M, t)                                                           \
  { _Pragma("unroll") for (int mf_ = 0; mf_ < 8; ++mf_) M[mf_] = mp[mf_][(t)]; }

#define COMPUTE(buf, M)                                                       \
  {                                                                           \
    const unsigned short* yb_ = &yL[buf][0];                                  \
    u16x8 bv00_ = *(const u16x8*)&yb_[boff[0][0]];                            \
    u16x8 bv01_ = *(const u16x8*)&yb_[boff[0][1]];                            \
    u16x8 bv10_ = *(const u16x8*)&yb_[boff[1][0]];                            \
    u16x8 bv11_ = *(const u16x8*)&yb_[boff[1][1]];                            \
    _Pragma("unroll")                                                         \
    for (int mf_ = 0; mf_ < 8; ++mf_) {                                       \
      const unsigned int lo_ = (unsigned int)M[mf_];                          \
      const unsigned int hw_ = (unsigned int)(M[mf_] >> 32);                  \
      const bf16x8 a0_ = expand8((lo_ >> hs) & 0xFFu);                        \
      const bf16x8 a1_ = expand8((hw_ >> hs) & 0xFFu);                        \
      acc[mf_][0] = __builtin_amdgcn_mfma_f32_16x16x32_bf16(                  \
          a0_, __builtin_bit_cast(bf16x8, bv00_), acc[mf_][0], 0, 0, 0);      \
      acc[mf_][0] = __builtin_amdgcn_mfma_f32_16x16x32_bf16(                  \
          a1_, __builtin_bit_cast(bf16x8, bv01_), acc[mf_][0], 0, 0, 0);      \
      acc[mf_][1] = __builtin_amdgcn_mfma_f32_16x16x32_bf16(                  \
          a0_, __builtin_bit_cast(bf16x8, bv10_), acc[mf_][1], 0, 0, 0);      \
      acc[mf_][1] = __builtin_amdgcn_mfma_f32_16x16x32_bf16(                  \
          a1_, __builtin_bit_cast(bf16x8, bv11_), acc[mf_][1], 0, 0, 0);      \
    }                                                                         \
  }

  // Prologue: stream = [Y0, Y1, Y2, Ma(0) x8] = 11 outstanding.
  STAGE(0, 0);
  STAGE(1, 1);
  STAGE(2, 2);
  LOADM(Ma, 0);

  // 64 K-steps, 2x unrolled (even: use Ma load Mb; odd: use Mb load Ma).
  for (int t2 = 0; t2 < 64; t2 += 2) {
    // even step t = t2
    BARRIER; FENCE;
    STAGE((t2 + 3) & 3, (t2 + 3) & 63);
    LOADM(Mb, (t2 + 1) & 63);
    WAIT_VM9;                 // M(t) + Y(t) guaranteed complete
    COMPUTE(t2 & 3, Ma);
    // odd step t = t2+1
    BARRIER; FENCE;
    STAGE((t2 + 4) & 3, (t2 + 4) & 63);
    LOADM(Ma, (t2 + 2) & 63);
    WAIT_VM9;
    COMPUTE((t2 + 1) & 3, Mb);
  }
  asm volatile("s_waitcnt vmcnt(0)" ::: "memory");  // drain wrapped dummies

  // C partial write (bf16 plane ksp in d_out)
#pragma unroll
  for (int mf = 0; mf < 8; ++mf)
#pragma unroll
    for (int nf = 0; nf < 2; ++nf) {
      const int col = ncol0 + (wc << 5) + nf * 16 + rl;
#pragma unroll
      for (int r = 0; r < 4; ++r) {
        const int row = i0 + (wr << 7) + mf * 16 + hi4 * 4 + r;
        Cp[((size_t)ksp * NN + row) * 512 + col] = f2bf(acc[mf][nf][r]);
      }
    }
#undef BARRIER
#undef FENCE
#undef WAIT_VM9
#undef STAGE
#undef LOADM
#undef COMPUTE
}

// ---------------------------------------------------------------------------
// K3: epiA.  F[i][col] = deg>0 ? (Cp0+Cp1)/deg + b_neigh[fo] : 0   (bf16)
// Reads Cp planes from d_out, writes F into ws (reusing the mask region).
// ---------------------------------------------------------------------------
__global__ __launch_bounds__(256) void epiA_kernel(
    const unsigned short* __restrict__ Cp, const float* __restrict__ degp,
    const float* __restrict__ bneigh, unsigned short* __restrict__ F) {
  const int idx = (blockIdx.x << 8) + threadIdx.x;   // 524288 threads
  const size_t cidx = (size_t)idx * 8;
  const int i = (int)(cidx >> 9);
  const int fo0 = (int)(cidx & 511) & 63;
  const float deg = degp[i] + degp[NN + i];
  const bool has = deg > 0.5f;
  const float r = has ? 1.0f / deg : 0.0f;
  u16x8 c0 = *(const u16x8*)&Cp[cidx];
  u16x8 c1 = *(const u16x8*)&Cp[(size_t)NN * 512 + cidx];
  float4 bn0 = *(const float4*)&bneigh[fo0];
  float4 bn1 = *(const float4*)&bneigh[fo0 + 4];
  u16x8 f;
#pragma unroll
  for (int j = 0; j < 8; ++j) {
    const float bn = (j < 4) ? ((const float*)&bn0)[j] : ((const float*)&bn1)[j - 4];
    const float v = (bf2f(c0[j]) + bf2f(c1[j])) * r + bn;
    f[j] = has ? f2bf(v) : (unsigned short)0;
  }
  *(u16x8*)&F[cidx] = f;
}

// ---------------------------------------------------------------------------
// K4: epiB.  One wave per (b,i); lane = fo.
// v = relu(S + F); LayerNorm over fo; write f32 to d_out.
// ---------------------------------------------------------------------------
__global__ __launch_bounds__(256) void epiB_kernel(
    const unsigned short* __restrict__ F, const unsigned short* __restrict__ Sbf,
    const float* __restrict__ gamma, const float* __restrict__ beta,
    float* __restrict__ out) {
  const int lane = threadIdx.x & 63;
  const int wid = (blockIdx.x << 2) + (threadIdx.x >> 6);
  const int b = wid >> 13;
  const int i = wid & (NN - 1);
  const float sv = bf2f(Sbf[((size_t)b * NN + i) * 64 + lane]);
  const float fv = bf2f(F[(size_t)i * 512 + b * 64 + lane]);
  float v = fmaxf(sv + fv, 0.0f);
  float s1 = v, s2 = v * v;
#pragma unroll
  for (int m = 1; m < 64; m <<= 1) {
    s1 += __shfl_xor(s1, m);
    s2 += __shfl_xor(s2, m);
  }
  const float mu = s1 * 0.015625f;
  const float var = s2 * 0.015625f - mu * mu;
  const float o = (v - mu) * rsqrtf(var + 1e-5f) * gamma[lane] + beta[lane];
  out[((size_t)b * NN + i) * 64 + lane] = o;
}

extern "C" void kernel_launch(void* const* d_in, const int* in_sizes, int n_in,
                              void* d_out, int out_size, void* d_ws, size_t ws_size,
                              hipStream_t stream) {
  (void)in_sizes; (void)n_in; (void)out_size; (void)ws_size;
  const float* x      = (const float*)d_in[0];
  const int*   adj    = (const int*)d_in[1];
  const float* Wself  = (const float*)d_in[2];
  const float* bself  = (const float*)d_in[3];
  const float* Wneigh = (const float*)d_in[4];
  const float* bneigh = (const float*)d_in[5];
  const float* gamma  = (const float*)d_in[6];
  const float* beta   = (const float*)d_in[7];
  char* ws = (char*)d_ws;
  // ws layout (25,231,360 B total):
  unsigned short*     Yt   = (unsigned short*)ws;                    //  8 MB
  unsigned long long* mask = (unsigned long long*)(ws + 8388608);    //  8 MB
  unsigned short*     Sbf  = (unsigned short*)(ws + 16777216);       //  8 MB
  float*              degp = (float*)(ws + 25165824);                // 64 KB
  unsigned short*     F    = (unsigned short*)(ws + 8388608);        // alias mask (dead after gemm)
  unsigned short*     Cp   = (unsigned short*)d_out;                 // 2 bf16 planes in d_out
  float*              out  = (float*)d_out;

  pack_kernel<<<dim3(4096), dim3(256), 0, stream>>>(adj, mask, degp);
  prep_kernel<<<dim3(1024), dim3(256), 0, stream>>>(x, Wself, bself, Wneigh, Yt, Sbf);
  gemm_kernel<<<dim3(256), dim3(512), 0, stream>>>(mask, Yt, Cp);
  epiA_kernel<<<dim3(2048), dim3(256), 0, stream>>>(Cp, degp, bneigh, F);
  epiB_kernel<<<dim3(16384), dim3(256), 0, stream>>>(F, Sbf, gamma, beta, out);
}

// Round 7
// 176.854 us; speedup vs baseline: 2.2395x; 1.7745x over previous
//
#include <hip/hip_runtime.h>

#define NN 8192

typedef __bf16 bf16x8 __attribute__((ext_vector_type(8)));
typedef float f32x4 __attribute__((ext_vector_type(4)));
typedef unsigned short u16x8 __attribute__((ext_vector_type(8)));
typedef int i32x4 __attribute__((ext_vector_type(4)));
typedef int i32x16 __attribute__((ext_vector_type(16)));

#define GLOBAL_AS __attribute__((address_space(1)))
#define LDS_AS __attribute__((address_space(3)))

__device__ __forceinline__ unsigned short f2bf(float f) {
  unsigned int u = __builtin_bit_cast(unsigned int, f);
  u += 0x7FFFu + ((u >> 16) & 1u);   // RNE
  return (unsigned short)(u >> 16);
}
__device__ __forceinline__ float bf2f(unsigned short b) {
  unsigned int u = ((unsigned int)b) << 16;
  return __builtin_bit_cast(float, u);
}

// 16 adjacency bits -> 16 i8 {0,1} in 4 u32 (byte j of u32 r = bit 4r+j).
// Bit-spread: x*0x204081 puts bit i at positions i, i+7, i+14, i+21;
// & 0x01010101 keeps exactly one copy per byte.  Full-rate (mul24-able).
__device__ __forceinline__ i32x4 expA(unsigned int h) {
  i32x4 a;
  a[0] = (int)((((h      ) & 0xFu) * 0x204081u) & 0x01010101u);
  a[1] = (int)((((h >> 4 ) & 0xFu) * 0x204081u) & 0x01010101u);
  a[2] = (int)((((h >> 8 ) & 0xFu) * 0x204081u) & 0x01010101u);
  a[3] = (int)((((h >> 12) & 0xFu) * 0x204081u) & 0x01010101u);
  return a;
}

// ---------------------------------------------------------------------------
// K0: pack.  Streams adj (268 MB) ONCE at HBM BW; emits
//   mask[row][c] : uint64, bit b = (adj[row][c*64+b] > 0)        (8 MB)
//   degp[half][row] : popcount of row half                        (64 KB)
// ---------------------------------------------------------------------------
__global__ __launch_bounds__(256) void pack_kernel(
    const int* __restrict__ adj, unsigned long long* __restrict__ mask,
    float* __restrict__ degp) {
  __shared__ unsigned long long sm[4][64];
  const int lane = threadIdx.x & 63;
  const int wv = threadIdx.x >> 6;
  const int wid = (blockIdx.x << 2) + wv;
  const int row = wid >> 1, half = wid & 1;
  const int* src = adj + (size_t)row * NN + half * 4096 + lane;
  int deg = 0;
#pragma unroll
  for (int c = 0; c < 64; ++c) {
    int v = src[c * 64];
    unsigned long long m = __ballot(v > 0);
    if (lane == 0) sm[wv][c] = m;
    deg += (int)__popcll(m);
  }
  __syncthreads();
  mask[(size_t)row * 128 + half * 64 + lane] = sm[wv][lane];
  if (lane == 0) degp[half * NN + row] = (float)deg;
}

// ---------------------------------------------------------------------------
// K1: prep.  Per block: one batch b, 64 nodes.  Computes
//   Yq[(b*64+fo)][j] = i8( round(16 * x[b,j,:] @ W_neigh[:,fo]) )  (transposed)
//   Sbf[b,j,fo]      = bf16( x[b,j,:] @ W_self [:,fo] + b_self[fo] )
// ---------------------------------------------------------------------------
__global__ __launch_bounds__(256) void prep_kernel(
    const float* __restrict__ x, const float* __restrict__ Wself,
    const float* __restrict__ bself, const float* __restrict__ Wneigh,
    char* __restrict__ Yq, unsigned short* __restrict__ Sout) {
  __shared__ __align__(16) unsigned short xa[64 * 64];    // [j][k] swizzled
  __shared__ __align__(16) unsigned short bm[128 * 64];   // [n][k]; n<64: Wneigh, n>=64: Wself
  const int t = threadIdx.x;
  const int b = blockIdx.x >> 7;
  const int j0 = (blockIdx.x & 127) << 6;

  {
    const float* Wsel = (t < 128) ? Wneigh : Wself;
    const int tt = t & 127;
    const int k = tt >> 1;
    const int c0 = (tt & 1) << 5;
    const int nbase = (t < 128) ? 0 : 64;
    const float4* src = (const float4*)(Wsel + k * 64 + c0);
#pragma unroll
    for (int q = 0; q < 8; ++q) {
      float4 v = src[q];
      int n0 = nbase + c0 + q * 4;
      int n;
      n = n0 + 0; bm[n * 64 + (k ^ ((n & 7) << 3))] = f2bf(v.x);
      n = n0 + 1; bm[n * 64 + (k ^ ((n & 7) << 3))] = f2bf(v.y);
      n = n0 + 2; bm[n * 64 + (k ^ ((n & 7) << 3))] = f2bf(v.z);
      n = n0 + 3; bm[n * 64 + (k ^ ((n & 7) << 3))] = f2bf(v.w);
    }
  }
  {
    const int j = t >> 2, q = t & 3;
    const float* xrow = x + ((size_t)b * NN + j0 + j) * 64 + q * 16;
    float4 v0 = *(const float4*)(xrow + 0);
    float4 v1 = *(const float4*)(xrow + 4);
    float4 v2 = *(const float4*)(xrow + 8);
    float4 v3 = *(const float4*)(xrow + 12);
    u16x8 p0, p1;
    p0[0] = f2bf(v0.x); p0[1] = f2bf(v0.y); p0[2] = f2bf(v0.z); p0[3] = f2bf(v0.w);
    p0[4] = f2bf(v1.x); p0[5] = f2bf(v1.y); p0[6] = f2bf(v1.z); p0[7] = f2bf(v1.w);
    p1[0] = f2bf(v2.x); p1[1] = f2bf(v2.y); p1[2] = f2bf(v2.z); p1[3] = f2bf(v2.w);
    p1[4] = f2bf(v3.x); p1[5] = f2bf(v3.y); p1[6] = f2bf(v3.z); p1[7] = f2bf(v3.w);
    const int base = q * 16;
    const int sw = (j & 7) << 3;
    *(u16x8*)&xa[j * 64 + (base ^ sw)] = p0;
    *(u16x8*)&xa[j * 64 + ((base + 8) ^ sw)] = p1;
  }
  __syncthreads();

  const int lane = t & 63, w = t >> 6;
  const int rl = lane & 15, hi = lane >> 4;
  f32x4 acc[8];
#pragma unroll
  for (int i = 0; i < 8; ++i) acc[i] = (f32x4){0.f, 0.f, 0.f, 0.f};

#pragma unroll
  for (int ks = 0; ks < 2; ++ks) {
    const int r = w * 16 + rl;
    const int kel = ks * 32 + hi * 8;
    bf16x8 af = __builtin_bit_cast(bf16x8, *(u16x8*)&xa[r * 64 + (kel ^ ((r & 7) << 3))]);
#pragma unroll
    for (int nf = 0; nf < 8; ++nf) {
      const int n = nf * 16 + rl;
      bf16x8 bv = __builtin_bit_cast(bf16x8, *(u16x8*)&bm[n * 64 + (kel ^ ((n & 7) << 3))]);
      acc[nf] = __builtin_amdgcn_mfma_f32_16x16x32_bf16(af, bv, acc[nf], 0, 0, 0);
    }
  }
#pragma unroll
  for (int nf = 0; nf < 8; ++nf) {
    if (nf < 4) {
      const int n = nf * 16 + rl;             // global col = b*64+n
      // 4 consecutive j values -> one packed u32 of 4 i8 (scale 16, RNE)
      unsigned int pkt = 0;
#pragma unroll
      for (int r = 0; r < 4; ++r) {
        float v = fminf(fmaxf(acc[nf][r] * 16.0f, -127.0f), 127.0f);
        int iv = __float2int_rn(v);
        pkt |= ((unsigned int)(iv & 0xFF)) << (r * 8);
      }
      *(unsigned int*)(Yq + (size_t)(b * 64 + n) * NN + j0 + w * 16 + hi * 4) = pkt;
    } else {
      const int fo = (nf - 4) * 16 + rl;
      const float bsv = bself[fo];
#pragma unroll
      for (int r = 0; r < 4; ++r) {
        const int jj = w * 16 + hi * 4 + r;
        Sout[((size_t)b * NN + j0 + jj) * 64 + fo] = f2bf(acc[nf][r] + bsv);
      }
    }
  }
}

// ---------------------------------------------------------------------------
// K2: big GEMM  C[i][n] = sum_j bit(i,j) * Yq[n][j] / 16,  n = b*64+fo.
// i8 MFMA (v_mfma_i32_32x32x32_i8): A expanded from bits at 2-3 VALU ops per
// 4 elems (bit-spread multiply), B = quantized Y i8.  BM=512 (8 waves x 64
// rows), BN=64, ksp=2 -> grid 256 (1 block/CU, 2 waves/SIMD).
// K-outer step = 128 elems.  Y: 8-buffer LDS ring (8 x 8KB), staged 3 ahead
// via global_load_lds (src granule-swizzled, dest linear).  Mask: one
// dwordx4 per row-frag per step, register double-buffered.
// Race-safe pipeline: per iter {LOADM(t+1); STAGE(t+3); s_waitcnt vmcnt(4);
// s_barrier} -- each wave drains its own stage BEFORE the barrier, so after
// the barrier ALL waves' portions of tile t are in LDS.  8-deep ring makes
// the overwrite distance (4 steps) safe with a single barrier per iter.
// C partials: f2bf(acc/16) into d_out planes (combined by epiA).
// ---------------------------------------------------------------------------
__global__ __launch_bounds__(512, 1) void gemm_kernel(
    const i32x4* __restrict__ mask,     // [8192][64] x 16B view of u64 masks
    const char* __restrict__ Yq,        // [512][8192] i8
    unsigned short* __restrict__ Cp) {
  __shared__ __align__(16) char yL[8][8192];   // 64 KB ring
  const int tid = threadIdx.x;
  const int lane = tid & 63, w = tid >> 6;
  const int nid = ((blockIdx.x & 7) << 5) + (blockIdx.x >> 3);
  const int q = nid >> 4, mb = nid & 15;
  const int ksp = q >> 3, nb = q & 7;
  const int i0 = mb << 9;            // 512 rows
  const int kbase = ksp << 12;       // k offset (elems)
  const int ncol0 = nb << 6;         // 64 cols
  const int l31 = lane & 31, l5 = lane >> 5;
  const int hs16 = l5 << 4;

  // Y staging: wave w stages cols [w*8, w*8+8); lane -> (col, granule16).
  // LDS dest is linear (base + lane*16 == col*128 + (lane&7)*16); the bank
  // swizzle granule^(col&7) is applied on the SOURCE address (m173 pattern).
  const int cst = (w << 3) + (lane >> 3);
  const char* ysrc = Yq + (size_t)(ncol0 + cst) * NN + kbase
                     + (((lane & 7) ^ (cst & 7)) << 4);
  // mask pointers: row-frag mf in {0,1}: row = i0 + w*64 + mf*32 + l31
  const i32x4* mq0 = mask + (((size_t)(i0 + (w << 6) + l31)) << 6) + (ksp << 5);
  const i32x4* mq1 = mq0 + (32 << 6);

  // B-read LDS byte offsets per [nf][s] (granule-swizzled)
  int boff[2][4];
#pragma unroll
  for (int nf = 0; nf < 2; ++nf)
#pragma unroll
    for (int s = 0; s < 4; ++s) {
      const int col = (nf << 5) + l31;
      const int g = (s << 1) + l5;
      boff[nf][s] = (col << 7) + ((g ^ (col & 7)) << 4);
    }

  i32x16 acc[2][2];
#pragma unroll
  for (int mf = 0; mf < 2; ++mf)
#pragma unroll
    for (int nf = 0; nf < 2; ++nf)
#pragma unroll
      for (int e = 0; e < 16; ++e) acc[mf][nf][e] = 0;

#define BARRIER  __builtin_amdgcn_s_barrier()
#define FENCE    __builtin_amdgcn_sched_barrier(0)
#define WAIT_VM4 asm volatile("s_waitcnt vmcnt(4)" ::: "memory")

#define STAGE(t)                                                              \
  __builtin_amdgcn_global_load_lds(                                           \
      (GLOBAL_AS void*)const_cast<char*>(ysrc + (size_t)((t) & 31) * 128),    \
      (LDS_AS void*)&yL[(t) & 7][w << 10], 16, 0, 0)

#define COMPUTE(t, M0, M1)                                                    \
  {                                                                           \
    const char* yb_ = &yL[(t) & 7][0];                                        \
    _Pragma("unroll")                                                         \
    for (int s_ = 0; s_ < 4; ++s_) {                                          \
      i32x4 b0_ = *(const i32x4*)(yb_ + boff[0][s_]);                         \
      i32x4 b1_ = *(const i32x4*)(yb_ + boff[1][s_]);                         \
      unsigned int h0_ = ((unsigned int)(M0)[s_] >> hs16) & 0xFFFFu;          \
      unsigned int h1_ = ((unsigned int)(M1)[s_] >> hs16) & 0xFFFFu;          \
      i32x4 a0_ = expA(h0_);                                                  \
      i32x4 a1_ = expA(h1_);                                                  \
      acc[0][0] = __builtin_amdgcn_mfma_i32_32x32x32_i8(a0_, b0_, acc[0][0], 0, 0, 0); \
      acc[0][1] = __builtin_amdgcn_mfma_i32_32x32x32_i8(a0_, b1_, acc[0][1], 0, 0, 0); \
      acc[1][0] = __builtin_amdgcn_mfma_i32_32x32x32_i8(a1_, b0_, acc[1][0], 0, 0, 0); \
      acc[1][1] = __builtin_amdgcn_mfma_i32_32x32x32_i8(a1_, b1_, acc[1][1], 0, 0, 0); \
    }                                                                         \
  }

  i32x4 Ma0, Ma1, Mb0, Mb1;
  // Prologue order [S0, S1, M(0)x2, S2] so iter0's vmcnt(4) drains S0..M0.
  STAGE(0);
  STAGE(1);
  Ma0 = mq0[0]; Ma1 = mq1[0];
  STAGE(2);

  for (int t2 = 0; t2 < 32; t2 += 2) {
    // iter t2: consume Ma/buf[t2], prefetch M(t2+1) + Y(t2+3)
    Mb0 = mq0[(t2 + 1) & 31]; Mb1 = mq1[(t2 + 1) & 31];
    STAGE(t2 + 3);
    WAIT_VM4;            // own S(t2) drained (and M(t2) via compiler dep)
    BARRIER; FENCE;      // => ALL waves' S(t2) portions now in LDS
    COMPUTE(t2, Ma0, Ma1);
    // iter t2+1
    Ma0 = mq0[(t2 + 2) & 31]; Ma1 = mq1[(t2 + 2) & 31];
    STAGE(t2 + 4);
    WAIT_VM4;
    BARRIER; FENCE;
    COMPUTE(t2 + 1, Mb0, Mb1);
  }

  // C partial write: dequant (x 1/16) -> bf16 plane ksp in d_out.
  // C layout: col = lane&31, row = (reg&3) + 8*(reg>>2) + 4*(lane>>5).
#pragma unroll
  for (int mf = 0; mf < 2; ++mf)
#pragma unroll
    for (int nf = 0; nf < 2; ++nf) {
      const int col = ncol0 + (nf << 5) + l31;
#pragma unroll
      for (int r = 0; r < 16; ++r) {
        const int row = i0 + (w << 6) + (mf << 5) + (r & 3) + ((r >> 2) << 3) + (l5 << 2);
        Cp[((size_t)ksp * NN + row) * 512 + col] = f2bf((float)acc[mf][nf][r] * 0.0625f);
      }
    }
#undef BARRIER
#undef FENCE
#undef WAIT_VM4
#undef STAGE
#undef COMPUTE
}

// ---------------------------------------------------------------------------
// K3: epiA.  F[i][col] = deg>0 ? (Cp0+Cp1)/deg + b_neigh[fo] : 0   (bf16)
// Reads Cp planes from d_out, writes F into ws (reusing the mask region).
// ---------------------------------------------------------------------------
__global__ __launch_bounds__(256) void epiA_kernel(
    const unsigned short* __restrict__ Cp, const float* __restrict__ degp,
    const float* __restrict__ bneigh, unsigned short* __restrict__ F) {
  const int idx = (blockIdx.x << 8) + threadIdx.x;   // 524288 threads
  const size_t cidx = (size_t)idx * 8;
  const int i = (int)(cidx >> 9);
  const int fo0 = (int)(cidx & 511) & 63;
  const float deg = degp[i] + degp[NN + i];
  const bool has = deg > 0.5f;
  const float r = has ? 1.0f / deg : 0.0f;
  u16x8 c0 = *(const u16x8*)&Cp[cidx];
  u16x8 c1 = *(const u16x8*)&Cp[(size_t)NN * 512 + cidx];
  float4 bn0 = *(const float4*)&bneigh[fo0];
  float4 bn1 = *(const float4*)&bneigh[fo0 + 4];
  u16x8 f;
#pragma unroll
  for (int j = 0; j < 8; ++j) {
    const float bn = (j < 4) ? ((const float*)&bn0)[j] : ((const float*)&bn1)[j - 4];
    const float v = (bf2f(c0[j]) + bf2f(c1[j])) * r + bn;
    f[j] = has ? f2bf(v) : (unsigned short)0;
  }
  *(u16x8*)&F[cidx] = f;
}

// ---------------------------------------------------------------------------
// K4: epiB.  One wave per (b,i); lane = fo.
// v = relu(S + F); LayerNorm over fo; write f32 to d_out.
// ---------------------------------------------------------------------------
__global__ __launch_bounds__(256) void epiB_kernel(
    const unsigned short* __restrict__ F, const unsigned short* __restrict__ Sbf,
    const float* __restrict__ gamma, const float* __restrict__ beta,
    float* __restrict__ out) {
  const int lane = threadIdx.x & 63;
  const int wid = (blockIdx.x << 2) + (threadIdx.x >> 6);
  const int b = wid >> 13;
  const int i = wid & (NN - 1);
  const float sv = bf2f(Sbf[((size_t)b * NN + i) * 64 + lane]);
  const float fv = bf2f(F[(size_t)i * 512 + b * 64 + lane]);
  float v = fmaxf(sv + fv, 0.0f);
  float s1 = v, s2 = v * v;
#pragma unroll
  for (int m = 1; m < 64; m <<= 1) {
    s1 += __shfl_xor(s1, m);
    s2 += __shfl_xor(s2, m);
  }
  const float mu = s1 * 0.015625f;
  const float var = s2 * 0.015625f - mu * mu;
  const float o = (v - mu) * rsqrtf(var + 1e-5f) * gamma[lane] + beta[lane];
  out[((size_t)b * NN + i) * 64 + lane] = o;
}

extern "C" void kernel_launch(void* const* d_in, const int* in_sizes, int n_in,
                              void* d_out, int out_size, void* d_ws, size_t ws_size,
                              hipStream_t stream) {
  (void)in_sizes; (void)n_in; (void)out_size; (void)ws_size;
  const float* x      = (const float*)d_in[0];
  const int*   adj    = (const int*)d_in[1];
  const float* Wself  = (const float*)d_in[2];
  const float* bself  = (const float*)d_in[3];
  const float* Wneigh = (const float*)d_in[4];
  const float* bneigh = (const float*)d_in[5];
  const float* gamma  = (const float*)d_in[6];
  const float* beta   = (const float*)d_in[7];
  char* ws = (char*)d_ws;
  // ws layout (20 MB + 64 KB):
  char*               Yq   = ws;                                     //  4 MB
  unsigned long long* mask = (unsigned long long*)(ws + 4194304);    //  8 MB
  unsigned short*     Sbf  = (unsigned short*)(ws + 12582912);       //  8 MB
  float*              degp = (float*)(ws + 20971520);                // 64 KB
  unsigned short*     F    = (unsigned short*)(ws + 4194304);        // alias mask (dead after gemm)
  unsigned short*     Cp   = (unsigned short*)d_out;                 // 2 bf16 planes in d_out
  float*              out  = (float*)d_out;

  pack_kernel<<<dim3(4096), dim3(256), 0, stream>>>(adj, mask, degp);
  prep_kernel<<<dim3(1024), dim3(256), 0, stream>>>(x, Wself, bself, Wneigh, Yq, Sbf);
  gemm_kernel<<<dim3(256), dim3(512), 0, stream>>>((const i32x4*)mask, Yq, Cp);
  epiA_kernel<<<dim3(2048), dim3(256), 0, stream>>>(Cp, degp, bneigh, F);
  epiB_kernel<<<dim3(16384), dim3(256), 0, stream>>>(F, Sbf, gamma, beta, out);
}

// Round 8
// 128.219 us; speedup vs baseline: 3.0890x; 1.3793x over previous
//
#include <hip/hip_runtime.h>

#define NN 8192

typedef __bf16 bf16x8 __attribute__((ext_vector_type(8)));
typedef float f32x4 __attribute__((ext_vector_type(4)));
typedef unsigned short u16x8 __attribute__((ext_vector_type(8)));
typedef int i32x4 __attribute__((ext_vector_type(4)));
typedef int i32x16 __attribute__((ext_vector_type(16)));

#define GLOBAL_AS __attribute__((address_space(1)))
#define LDS_AS __attribute__((address_space(3)))

__device__ __forceinline__ unsigned short f2bf(float f) {
  unsigned int u = __builtin_bit_cast(unsigned int, f);
  u += 0x7FFFu + ((u >> 16) & 1u);   // RNE
  return (unsigned short)(u >> 16);
}
__device__ __forceinline__ float bf2f(unsigned short b) {
  unsigned int u = ((unsigned int)b) << 16;
  return __builtin_bit_cast(float, u);
}

// 16 adjacency bits -> 16 i8 {0,1} in 4 u32 (byte j of u32 r = bit 4r+j).
// Bit-spread: x*0x204081 puts bit i at bit positions i,i+7,i+14,i+21;
// & 0x01010101 keeps one copy per byte.  ~4 full-rate VALU ops per 4 elems.
__device__ __forceinline__ i32x4 expA(unsigned int h) {
  i32x4 a;
  a[0] = (int)((((h      ) & 0xFu) * 0x204081u) & 0x01010101u);
  a[1] = (int)((((h >> 4 ) & 0xFu) * 0x204081u) & 0x01010101u);
  a[2] = (int)((((h >> 8 ) & 0xFu) * 0x204081u) & 0x01010101u);
  a[3] = (int)((((h >> 12) & 0xFu) * 0x204081u) & 0x01010101u);
  return a;
}

// ---------------------------------------------------------------------------
// K0: pack.  Streams adj (268 MB) ONCE; emits
//   mask[row][w] : u64, bit b = (adj[row][w*64+b] > 0)          (8 MB)
//   degp[half][row] : popcount of row half                      (64 KB)
// Per-thread word assembly (NO ballot, NO LDS): lane owns 64 consecutive
// elems (16 x int4 loads, fully independent), builds its u64 in VALU,
// writes one coalesced 8B store.  deg via 6-step shfl_xor reduce.
// ---------------------------------------------------------------------------
__global__ __launch_bounds__(256) void pack_kernel(
    const int* __restrict__ adj, unsigned long long* __restrict__ mask,
    float* __restrict__ degp) {
  const int lane = threadIdx.x & 63;
  const int wv = threadIdx.x >> 6;
  const int wid = (blockIdx.x << 2) + wv;
  const int row = wid >> 1, half = wid & 1;
  const int* src = adj + (size_t)row * NN + half * 4096 + lane * 64;
  unsigned long long word = 0;
#pragma unroll
  for (int c = 0; c < 16; ++c) {
    int4 v = *(const int4*)(src + c * 4);
    unsigned int nib = (unsigned int)(v.x > 0)
                     | ((unsigned int)(v.y > 0) << 1)
                     | ((unsigned int)(v.z > 0) << 2)
                     | ((unsigned int)(v.w > 0) << 3);
    word |= ((unsigned long long)nib) << (c * 4);
  }
  mask[(size_t)row * 128 + half * 64 + lane] = word;
  int deg = (int)__popcll(word);
#pragma unroll
  for (int m = 1; m < 64; m <<= 1) deg += __shfl_xor(deg, m);
  if (lane == 0) degp[half * NN + row] = (float)deg;
}

// ---------------------------------------------------------------------------
// K1: prep.  Per block: one batch b, 64 nodes.  Computes
//   Yq[(b*64+fo)][j] = i8( round(16 * x[b,j,:] @ W_neigh[:,fo]) )  (transposed)
//   Sbf[b,j,fo]      = bf16( x[b,j,:] @ W_self [:,fo] + b_self[fo] )
// ---------------------------------------------------------------------------
__global__ __launch_bounds__(256) void prep_kernel(
    const float* __restrict__ x, const float* __restrict__ Wself,
    const float* __restrict__ bself, const float* __restrict__ Wneigh,
    char* __restrict__ Yq, unsigned short* __restrict__ Sout) {
  __shared__ __align__(16) unsigned short xa[64 * 64];    // [j][k] swizzled
  __shared__ __align__(16) unsigned short bm[128 * 64];   // [n][k]; n<64: Wneigh, n>=64: Wself
  const int t = threadIdx.x;
  const int b = blockIdx.x >> 7;
  const int j0 = (blockIdx.x & 127) << 6;

  {
    const float* Wsel = (t < 128) ? Wneigh : Wself;
    const int tt = t & 127;
    const int k = tt >> 1;
    const int c0 = (tt & 1) << 5;
    const int nbase = (t < 128) ? 0 : 64;
    const float4* src = (const float4*)(Wsel + k * 64 + c0);
#pragma unroll
    for (int q = 0; q < 8; ++q) {
      float4 v = src[q];
      int n0 = nbase + c0 + q * 4;
      int n;
      n = n0 + 0; bm[n * 64 + (k ^ ((n & 7) << 3))] = f2bf(v.x);
      n = n0 + 1; bm[n * 64 + (k ^ ((n & 7) << 3))] = f2bf(v.y);
      n = n0 + 2; bm[n * 64 + (k ^ ((n & 7) << 3))] = f2bf(v.z);
      n = n0 + 3; bm[n * 64 + (k ^ ((n & 7) << 3))] = f2bf(v.w);
    }
  }
  {
    const int j = t >> 2, q = t & 3;
    const float* xrow = x + ((size_t)b * NN + j0 + j) * 64 + q * 16;
    float4 v0 = *(const float4*)(xrow + 0);
    float4 v1 = *(const float4*)(xrow + 4);
    float4 v2 = *(const float4*)(xrow + 8);
    float4 v3 = *(const float4*)(xrow + 12);
    u16x8 p0, p1;
    p0[0] = f2bf(v0.x); p0[1] = f2bf(v0.y); p0[2] = f2bf(v0.z); p0[3] = f2bf(v0.w);
    p0[4] = f2bf(v1.x); p0[5] = f2bf(v1.y); p0[6] = f2bf(v1.z); p0[7] = f2bf(v1.w);
    p1[0] = f2bf(v2.x); p1[1] = f2bf(v2.y); p1[2] = f2bf(v2.z); p1[3] = f2bf(v2.w);
    p1[4] = f2bf(v3.x); p1[5] = f2bf(v3.y); p1[6] = f2bf(v3.z); p1[7] = f2bf(v3.w);
    const int base = q * 16;
    const int sw = (j & 7) << 3;
    *(u16x8*)&xa[j * 64 + (base ^ sw)] = p0;
    *(u16x8*)&xa[j * 64 + ((base + 8) ^ sw)] = p1;
  }
  __syncthreads();

  const int lane = t & 63, w = t >> 6;
  const int rl = lane & 15, hi = lane >> 4;
  f32x4 acc[8];
#pragma unroll
  for (int i = 0; i < 8; ++i) acc[i] = (f32x4){0.f, 0.f, 0.f, 0.f};

#pragma unroll
  for (int ks = 0; ks < 2; ++ks) {
    const int r = w * 16 + rl;
    const int kel = ks * 32 + hi * 8;
    bf16x8 af = __builtin_bit_cast(bf16x8, *(u16x8*)&xa[r * 64 + (kel ^ ((r & 7) << 3))]);
#pragma unroll
    for (int nf = 0; nf < 8; ++nf) {
      const int n = nf * 16 + rl;
      bf16x8 bv = __builtin_bit_cast(bf16x8, *(u16x8*)&bm[n * 64 + (kel ^ ((n & 7) << 3))]);
      acc[nf] = __builtin_amdgcn_mfma_f32_16x16x32_bf16(af, bv, acc[nf], 0, 0, 0);
    }
  }
#pragma unroll
  for (int nf = 0; nf < 8; ++nf) {
    if (nf < 4) {
      const int n = nf * 16 + rl;             // global col = b*64+n
      unsigned int pkt = 0;
#pragma unroll
      for (int r = 0; r < 4; ++r) {
        float v = fminf(fmaxf(acc[nf][r] * 16.0f, -127.0f), 127.0f);
        int iv = __float2int_rn(v);
        pkt |= ((unsigned int)(iv & 0xFF)) << (r * 8);
      }
      *(unsigned int*)(Yq + (size_t)(b * 64 + n) * NN + j0 + w * 16 + hi * 4) = pkt;
    } else {
      const int fo = (nf - 4) * 16 + rl;
      const float bsv = bself[fo];
#pragma unroll
      for (int r = 0; r < 4; ++r) {
        const int jj = w * 16 + hi * 4 + r;
        Sout[((size_t)b * NN + j0 + jj) * 64 + fo] = f2bf(acc[nf][r] + bsv);
      }
    }
  }
}

// ---------------------------------------------------------------------------
// K2: big GEMM  C[i][n] = sum_j bit(i,j) * Yq[n][j] / 16,  n = b*64+fo.
// i8 MFMA (v_mfma_i32_32x32x32_i8); BM=512 (8 waves x 64 rows), BN=64,
// ksp=2 -> grid 256 (1 block/CU).  K-step 128.  Y: 8-buffer LDS ring staged
// 3 ahead via global_load_lds; mask: dwordx4/row-frag/step, reg dbuf.
// Per iter {LOADM(t+1); STAGE(t+3); s_waitcnt vmcnt(4); s_barrier}.
// C bf16 partials (2 ksp planes) -> ws (combined by epi).
// ---------------------------------------------------------------------------
__global__ __launch_bounds__(512, 1) void gemm_kernel(
    const i32x4* __restrict__ mask,     // [8192][64] x 16B view of u64 masks
    const char* __restrict__ Yq,        // [512][8192] i8
    unsigned short* __restrict__ Cp) {
  __shared__ __align__(16) char yL[8][8192];   // 64 KB ring
  const int tid = threadIdx.x;
  const int lane = tid & 63, w = tid >> 6;
  const int nid = ((blockIdx.x & 7) << 5) + (blockIdx.x >> 3);
  const int q = nid >> 4, mb = nid & 15;
  const int ksp = q >> 3, nb = q & 7;
  const int i0 = mb << 9;            // 512 rows
  const int kbase = ksp << 12;       // k offset (elems)
  const int ncol0 = nb << 6;         // 64 cols
  const int l31 = lane & 31, l5 = lane >> 5;
  const int hs16 = l5 << 4;

  // Y staging: wave w stages cols [w*8, w*8+8); src granule-swizzled, dest linear.
  const int cst = (w << 3) + (lane >> 3);
  const char* ysrc = Yq + (size_t)(ncol0 + cst) * NN + kbase
                     + (((lane & 7) ^ (cst & 7)) << 4);
  // mask pointers: row-frag mf in {0,1}: row = i0 + w*64 + mf*32 + l31
  const i32x4* mq0 = mask + (((size_t)(i0 + (w << 6) + l31)) << 6) + (ksp << 5);
  const i32x4* mq1 = mq0 + (32 << 6);

  // B-read LDS byte offsets per [nf][s] (granule-swizzled)
  int boff[2][4];
#pragma unroll
  for (int nf = 0; nf < 2; ++nf)
#pragma unroll
    for (int s = 0; s < 4; ++s) {
      const int col = (nf << 5) + l31;
      const int g = (s << 1) + l5;
      boff[nf][s] = (col << 7) + ((g ^ (col & 7)) << 4);
    }

  i32x16 acc[2][2];
#pragma unroll
  for (int mf = 0; mf < 2; ++mf)
#pragma unroll
    for (int nf = 0; nf < 2; ++nf)
#pragma unroll
      for (int e = 0; e < 16; ++e) acc[mf][nf][e] = 0;

#define BARRIER  __builtin_amdgcn_s_barrier()
#define FENCE    __builtin_amdgcn_sched_barrier(0)
#define WAIT_VM4 asm volatile("s_waitcnt vmcnt(4)" ::: "memory")

#define STAGE(t)                                                              \
  __builtin_amdgcn_global_load_lds(                                           \
      (GLOBAL_AS void*)const_cast<char*>(ysrc + (size_t)((t) & 31) * 128),    \
      (LDS_AS void*)&yL[(t) & 7][w << 10], 16, 0, 0)

#define COMPUTE(t, M0, M1)                                                    \
  {                                                                           \
    const char* yb_ = &yL[(t) & 7][0];                                        \
    _Pragma("unroll")                                                         \
    for (int s_ = 0; s_ < 4; ++s_) {                                          \
      i32x4 b0_ = *(const i32x4*)(yb_ + boff[0][s_]);                         \
      i32x4 b1_ = *(const i32x4*)(yb_ + boff[1][s_]);                         \
      unsigned int h0_ = ((unsigned int)(M0)[s_] >> hs16) & 0xFFFFu;          \
      unsigned int h1_ = ((unsigned int)(M1)[s_] >> hs16) & 0xFFFFu;          \
      i32x4 a0_ = expA(h0_);                                                  \
      i32x4 a1_ = expA(h1_);                                                  \
      acc[0][0] = __builtin_amdgcn_mfma_i32_32x32x32_i8(a0_, b0_, acc[0][0], 0, 0, 0); \
      acc[0][1] = __builtin_amdgcn_mfma_i32_32x32x32_i8(a0_, b1_, acc[0][1], 0, 0, 0); \
      acc[1][0] = __builtin_amdgcn_mfma_i32_32x32x32_i8(a1_, b0_, acc[1][0], 0, 0, 0); \
      acc[1][1] = __builtin_amdgcn_mfma_i32_32x32x32_i8(a1_, b1_, acc[1][1], 0, 0, 0); \
    }                                                                         \
  }

  i32x4 Ma0, Ma1, Mb0, Mb1;
  // Prologue order [S0, S1, M(0)x2, S2] so iter0's vmcnt(4) drains S0..M0.
  STAGE(0);
  STAGE(1);
  Ma0 = mq0[0]; Ma1 = mq1[0];
  STAGE(2);

  for (int t2 = 0; t2 < 32; t2 += 2) {
    // iter t2: consume Ma/buf[t2], prefetch M(t2+1) + Y(t2+3)
    Mb0 = mq0[(t2 + 1) & 31]; Mb1 = mq1[(t2 + 1) & 31];
    STAGE(t2 + 3);
    WAIT_VM4;            // own S(t2) drained (and M(t2) via compiler dep)
    BARRIER; FENCE;      // => ALL waves' S(t2) portions now in LDS
    COMPUTE(t2, Ma0, Ma1);
    // iter t2+1
    Ma0 = mq0[(t2 + 2) & 31]; Ma1 = mq1[(t2 + 2) & 31];
    STAGE(t2 + 4);
    WAIT_VM4;
    BARRIER; FENCE;
    COMPUTE(t2 + 1, Mb0, Mb1);
  }

  // C partial write: dequant (x 1/16) -> bf16 plane ksp in ws.
  // C layout: col = lane&31, row = (reg&3) + 8*(reg>>2) + 4*(lane>>5).
#pragma unroll
  for (int mf = 0; mf < 2; ++mf)
#pragma unroll
    for (int nf = 0; nf < 2; ++nf) {
      const int col = ncol0 + (nf << 5) + l31;
#pragma unroll
      for (int r = 0; r < 16; ++r) {
        const int row = i0 + (w << 6) + (mf << 5) + (r & 3) + ((r >> 2) << 3) + (l5 << 2);
        Cp[((size_t)ksp * NN + row) * 512 + col] = f2bf((float)acc[mf][nf][r] * 0.0625f);
      }
    }
#undef BARRIER
#undef FENCE
#undef WAIT_VM4
#undef STAGE
#undef COMPUTE
}

// ---------------------------------------------------------------------------
// K3: epi (fused, R3 structure).  One 64-lane wave per (b,i); lane = fo.
// v = relu(S + [deg>0]*((Cp0+Cp1)/max(deg,1) + b_neigh)); LayerNorm; f32 out.
// ---------------------------------------------------------------------------
__global__ __launch_bounds__(256) void epi_kernel(
    const unsigned short* __restrict__ Cp, const float* __restrict__ degp,
    const unsigned short* __restrict__ Sbf, const float* __restrict__ bneigh,
    const float* __restrict__ gamma, const float* __restrict__ beta,
    float* __restrict__ out) {
  const int lane = threadIdx.x & 63;
  const int wid = (blockIdx.x << 2) + (threadIdx.x >> 6);
  const int b = wid >> 13;
  const int i = wid & (NN - 1);
  const float deg = degp[i] + degp[NN + i];
  const float rdeg = 1.0f / fmaxf(deg, 1.0f);
  const size_t cidx = (size_t)i * 512 + b * 64 + lane;
  const float c = bf2f(Cp[cidx]) + bf2f(Cp[(size_t)NN * 512 + cidx]);
  const float sv = bf2f(Sbf[((size_t)b * NN + i) * 64 + lane]);
  float v = sv + ((deg > 0.5f) ? (c * rdeg + bneigh[lane]) : 0.0f);
  v = fmaxf(v, 0.0f);
  float s1 = v, s2 = v * v;
#pragma unroll
  for (int m = 1; m < 64; m <<= 1) {
    s1 += __shfl_xor(s1, m);
    s2 += __shfl_xor(s2, m);
  }
  const float mu = s1 * 0.015625f;
  const float var = s2 * 0.015625f - mu * mu;
  const float o = (v - mu) * rsqrtf(var + 1e-5f) * gamma[lane] + beta[lane];
  out[((size_t)b * NN + i) * 64 + lane] = o;
}

extern "C" void kernel_launch(void* const* d_in, const int* in_sizes, int n_in,
                              void* d_out, int out_size, void* d_ws, size_t ws_size,
                              hipStream_t stream) {
  (void)in_sizes; (void)n_in; (void)out_size; (void)ws_size;
  const float* x      = (const float*)d_in[0];
  const int*   adj    = (const int*)d_in[1];
  const float* Wself  = (const float*)d_in[2];
  const float* bself  = (const float*)d_in[3];
  const float* Wneigh = (const float*)d_in[4];
  const float* bneigh = (const float*)d_in[5];
  const float* gamma  = (const float*)d_in[6];
  const float* beta   = (const float*)d_in[7];
  char* ws = (char*)d_ws;
  // ws layout (~37 MB):
  char*               Yq   = ws;                                     //  4 MB
  unsigned long long* mask = (unsigned long long*)(ws + 4194304);    //  8 MB
  unsigned short*     Sbf  = (unsigned short*)(ws + 12582912);       //  8 MB
  unsigned short*     Cp   = (unsigned short*)(ws + 20971520);       // 16.7 MB (2 planes)
  float*              degp = (float*)(ws + 37748736);                // 64 KB
  float*              out  = (float*)d_out;

  pack_kernel<<<dim3(4096), dim3(256), 0, stream>>>(adj, mask, degp);
  prep_kernel<<<dim3(1024), dim3(256), 0, stream>>>(x, Wself, bself, Wneigh, Yq, Sbf);
  gemm_kernel<<<dim3(256), dim3(512), 0, stream>>>((const i32x4*)mask, Yq, Cp);
  epi_kernel<<<dim3(16384), dim3(256), 0, stream>>>(Cp, degp, Sbf, bneigh, gamma, beta, out);
}

// Round 9
// 128.039 us; speedup vs baseline: 3.0934x; 1.0014x over previous
//
#include <hip/hip_runtime.h>

#define NN 8192

typedef __bf16 bf16x8 __attribute__((ext_vector_type(8)));
typedef float f32x4 __attribute__((ext_vector_type(4)));
typedef unsigned short u16x8 __attribute__((ext_vector_type(8)));
typedef int i32x4 __attribute__((ext_vector_type(4)));
typedef int i32x16 __attribute__((ext_vector_type(16)));

#define GLOBAL_AS __attribute__((address_space(1)))
#define LDS_AS __attribute__((address_space(3)))

__device__ __forceinline__ unsigned short f2bf(float f) {
  unsigned int u = __builtin_bit_cast(unsigned int, f);
  u += 0x7FFFu + ((u >> 16) & 1u);   // RNE
  return (unsigned short)(u >> 16);
}
__device__ __forceinline__ float bf2f(unsigned short b) {
  unsigned int u = ((unsigned int)b) << 16;
  return __builtin_bit_cast(float, u);
}

// 16 adjacency bits (low 16 of h; higher bits ignored) -> 16 i8 {0,1}.
// Bit-spread: x*0x204081 puts bit i at bit positions i,i+7,i+14,i+21;
// & 0x01010101 keeps one copy per byte.
__device__ __forceinline__ i32x4 expA(unsigned int h) {
  i32x4 a;
  a[0] = (int)((((h      ) & 0xFu) * 0x204081u) & 0x01010101u);
  a[1] = (int)((((h >> 4 ) & 0xFu) * 0x204081u) & 0x01010101u);
  a[2] = (int)((((h >> 8 ) & 0xFu) * 0x204081u) & 0x01010101u);
  a[3] = (int)((((h >> 12) & 0xFu) * 0x204081u) & 0x01010101u);
  return a;
}

// ---------------------------------------------------------------------------
// K0: pack.  Streams adj (268 MB) ONCE; emits
//   mask[row][w] : u64, bit b = (adj[row][w*64+b] > 0)          (8 MB)
//   degp[half][row] : popcount of row half                      (64 KB)
// ---------------------------------------------------------------------------
__global__ __launch_bounds__(256) void pack_kernel(
    const int* __restrict__ adj, unsigned long long* __restrict__ mask,
    float* __restrict__ degp) {
  const int lane = threadIdx.x & 63;
  const int wv = threadIdx.x >> 6;
  const int wid = (blockIdx.x << 2) + wv;
  const int row = wid >> 1, half = wid & 1;
  const int* src = adj + (size_t)row * NN + half * 4096 + lane * 64;
  unsigned long long word = 0;
#pragma unroll
  for (int c = 0; c < 16; ++c) {
    int4 v = *(const int4*)(src + c * 4);
    unsigned int nib = (unsigned int)(v.x > 0)
                     | ((unsigned int)(v.y > 0) << 1)
                     | ((unsigned int)(v.z > 0) << 2)
                     | ((unsigned int)(v.w > 0) << 3);
    word |= ((unsigned long long)nib) << (c * 4);
  }
  mask[(size_t)row * 128 + half * 64 + lane] = word;
  int deg = (int)__popcll(word);
#pragma unroll
  for (int m = 1; m < 64; m <<= 1) deg += __shfl_xor(deg, m);
  if (lane == 0) degp[half * NN + row] = (float)deg;
}

// ---------------------------------------------------------------------------
// K1: prep.  Per block: one batch b, 64 nodes.  Computes
//   Yq[(b*64+fo)][j] = i8( round(16 * x[b,j,:] @ W_neigh[:,fo]) )  (transposed)
//   Sbf[b,j,fo]      = bf16( x[b,j,:] @ W_self [:,fo] + b_self[fo] )
// ---------------------------------------------------------------------------
__global__ __launch_bounds__(256) void prep_kernel(
    const float* __restrict__ x, const float* __restrict__ Wself,
    const float* __restrict__ bself, const float* __restrict__ Wneigh,
    char* __restrict__ Yq, unsigned short* __restrict__ Sout) {
  __shared__ __align__(16) unsigned short xa[64 * 64];    // [j][k] swizzled
  __shared__ __align__(16) unsigned short bm[128 * 64];   // [n][k]; n<64: Wneigh, n>=64: Wself
  const int t = threadIdx.x;
  const int b = blockIdx.x >> 7;
  const int j0 = (blockIdx.x & 127) << 6;

  {
    const float* Wsel = (t < 128) ? Wneigh : Wself;
    const int tt = t & 127;
    const int k = tt >> 1;
    const int c0 = (tt & 1) << 5;
    const int nbase = (t < 128) ? 0 : 64;
    const float4* src = (const float4*)(Wsel + k * 64 + c0);
#pragma unroll
    for (int q = 0; q < 8; ++q) {
      float4 v = src[q];
      int n0 = nbase + c0 + q * 4;
      int n;
      n = n0 + 0; bm[n * 64 + (k ^ ((n & 7) << 3))] = f2bf(v.x);
      n = n0 + 1; bm[n * 64 + (k ^ ((n & 7) << 3))] = f2bf(v.y);
      n = n0 + 2; bm[n * 64 + (k ^ ((n & 7) << 3))] = f2bf(v.z);
      n = n0 + 3; bm[n * 64 + (k ^ ((n & 7) << 3))] = f2bf(v.w);
    }
  }
  {
    const int j = t >> 2, q = t & 3;
    const float* xrow = x + ((size_t)b * NN + j0 + j) * 64 + q * 16;
    float4 v0 = *(const float4*)(xrow + 0);
    float4 v1 = *(const float4*)(xrow + 4);
    float4 v2 = *(const float4*)(xrow + 8);
    float4 v3 = *(const float4*)(xrow + 12);
    u16x8 p0, p1;
    p0[0] = f2bf(v0.x); p0[1] = f2bf(v0.y); p0[2] = f2bf(v0.z); p0[3] = f2bf(v0.w);
    p0[4] = f2bf(v1.x); p0[5] = f2bf(v1.y); p0[6] = f2bf(v1.z); p0[7] = f2bf(v1.w);
    p1[0] = f2bf(v2.x); p1[1] = f2bf(v2.y); p1[2] = f2bf(v2.z); p1[3] = f2bf(v2.w);
    p1[4] = f2bf(v3.x); p1[5] = f2bf(v3.y); p1[6] = f2bf(v3.z); p1[7] = f2bf(v3.w);
    const int base = q * 16;
    const int sw = (j & 7) << 3;
    *(u16x8*)&xa[j * 64 + (base ^ sw)] = p0;
    *(u16x8*)&xa[j * 64 + ((base + 8) ^ sw)] = p1;
  }
  __syncthreads();

  const int lane = t & 63, w = t >> 6;
  const int rl = lane & 15, hi = lane >> 4;
  f32x4 acc[8];
#pragma unroll
  for (int i = 0; i < 8; ++i) acc[i] = (f32x4){0.f, 0.f, 0.f, 0.f};

#pragma unroll
  for (int ks = 0; ks < 2; ++ks) {
    const int r = w * 16 + rl;
    const int kel = ks * 32 + hi * 8;
    bf16x8 af = __builtin_bit_cast(bf16x8, *(u16x8*)&xa[r * 64 + (kel ^ ((r & 7) << 3))]);
#pragma unroll
    for (int nf = 0; nf < 8; ++nf) {
      const int n = nf * 16 + rl;
      bf16x8 bv = __builtin_bit_cast(bf16x8, *(u16x8*)&bm[n * 64 + (kel ^ ((n & 7) << 3))]);
      acc[nf] = __builtin_amdgcn_mfma_f32_16x16x32_bf16(af, bv, acc[nf], 0, 0, 0);
    }
  }
#pragma unroll
  for (int nf = 0; nf < 8; ++nf) {
    if (nf < 4) {
      const int n = nf * 16 + rl;             // global col = b*64+n
      unsigned int pkt = 0;
#pragma unroll
      for (int r = 0; r < 4; ++r) {
        float v = fminf(fmaxf(acc[nf][r] * 16.0f, -127.0f), 127.0f);
        int iv = __float2int_rn(v);
        pkt |= ((unsigned int)(iv & 0xFF)) << (r * 8);
      }
      *(unsigned int*)(Yq + (size_t)(b * 64 + n) * NN + j0 + w * 16 + hi * 4) = pkt;
    } else {
      const int fo = (nf - 4) * 16 + rl;
      const float bsv = bself[fo];
#pragma unroll
      for (int r = 0; r < 4; ++r) {
        const int jj = w * 16 + hi * 4 + r;
        Sout[((size_t)b * NN + j0 + jj) * 64 + fo] = f2bf(acc[nf][r] + bsv);
      }
    }
  }
}

// ---------------------------------------------------------------------------
// K2: big GEMM  C[i][n] = sum_j bit(i,j) * Yq[n][j] / 16,  n = b*64+fo.
// i8 MFMA; BM=512 (8 waves x 64 rows), BN=64, ksp=2 -> grid 256 (1 block/CU).
// K-step 128.  Y: 8-buffer LDS ring staged 3 ahead via global_load_lds;
// mask: dwordx4/row-frag/step, reg dbuf.  Counted vmcnt(4) + raw barrier.
// R9 changes: sched_barrier(0) -> empty-asm mem clobber (un-pins the
// scheduler, keeps ring safety); s_setprio(1) around the compute cluster;
// dead &0xFFFF removed from h extraction.
// ---------------------------------------------------------------------------
__global__ __launch_bounds__(512, 1) void gemm_kernel(
    const i32x4* __restrict__ mask,     // [8192][64] x 16B view of u64 masks
    const char* __restrict__ Yq,        // [512][8192] i8
    unsigned short* __restrict__ Cp) {
  __shared__ __align__(16) char yL[8][8192];   // 64 KB ring
  const int tid = threadIdx.x;
  const int lane = tid & 63, w = tid >> 6;
  const int nid = ((blockIdx.x & 7) << 5) + (blockIdx.x >> 3);
  const int q = nid >> 4, mb = nid & 15;
  const int ksp = q >> 3, nb = q & 7;
  const int i0 = mb << 9;            // 512 rows
  const int kbase = ksp << 12;       // k offset (elems)
  const int ncol0 = nb << 6;         // 64 cols
  const int l31 = lane & 31, l5 = lane >> 5;
  const int hs16 = l5 << 4;

  // Y staging: wave w stages cols [w*8, w*8+8); src granule-swizzled, dest linear.
  const int cst = (w << 3) + (lane >> 3);
  const char* ysrc = Yq + (size_t)(ncol0 + cst) * NN + kbase
                     + (((lane & 7) ^ (cst & 7)) << 4);
  // mask pointers: row-frag mf in {0,1}: row = i0 + w*64 + mf*32 + l31
  const i32x4* mq0 = mask + (((size_t)(i0 + (w << 6) + l31)) << 6) + (ksp << 5);
  const i32x4* mq1 = mq0 + (32 << 6);

  // B-read LDS byte offsets per [nf][s] (granule-swizzled)
  int boff[2][4];
#pragma unroll
  for (int nf = 0; nf < 2; ++nf)
#pragma unroll
    for (int s = 0; s < 4; ++s) {
      const int col = (nf << 5) + l31;
      const int g = (s << 1) + l5;
      boff[nf][s] = (col << 7) + ((g ^ (col & 7)) << 4);
    }

  i32x16 acc[2][2];
#pragma unroll
  for (int mf = 0; mf < 2; ++mf)
#pragma unroll
    for (int nf = 0; nf < 2; ++nf)
#pragma unroll
      for (int e = 0; e < 16; ++e) acc[mf][nf][e] = 0;

#define BARRIER  __builtin_amdgcn_s_barrier()
#define MEMBAR   asm volatile("" ::: "memory")
#define WAIT_VM4 asm volatile("s_waitcnt vmcnt(4)" ::: "memory")

#define STAGE(t)                                                              \
  __builtin_amdgcn_global_load_lds(                                           \
      (GLOBAL_AS void*)const_cast<char*>(ysrc + (size_t)((t) & 31) * 128),    \
      (LDS_AS void*)&yL[(t) & 7][w << 10], 16, 0, 0)

#define COMPUTE(t, M0, M1)                                                    \
  {                                                                           \
    const char* yb_ = &yL[(t) & 7][0];                                        \
    __builtin_amdgcn_s_setprio(1);                                            \
    _Pragma("unroll")                                                         \
    for (int s_ = 0; s_ < 4; ++s_) {                                          \
      i32x4 b0_ = *(const i32x4*)(yb_ + boff[0][s_]);                         \
      i32x4 b1_ = *(const i32x4*)(yb_ + boff[1][s_]);                         \
      unsigned int h0_ = (unsigned int)(M0)[s_] >> hs16;                      \
      unsigned int h1_ = (unsigned int)(M1)[s_] >> hs16;                      \
      i32x4 a0_ = expA(h0_);                                                  \
      i32x4 a1_ = expA(h1_);                                                  \
      acc[0][0] = __builtin_amdgcn_mfma_i32_32x32x32_i8(a0_, b0_, acc[0][0], 0, 0, 0); \
      acc[0][1] = __builtin_amdgcn_mfma_i32_32x32x32_i8(a0_, b1_, acc[0][1], 0, 0, 0); \
      acc[1][0] = __builtin_amdgcn_mfma_i32_32x32x32_i8(a1_, b0_, acc[1][0], 0, 0, 0); \
      acc[1][1] = __builtin_amdgcn_mfma_i32_32x32x32_i8(a1_, b1_, acc[1][1], 0, 0, 0); \
    }                                                                         \
    __builtin_amdgcn_s_setprio(0);                                            \
  }

  i32x4 Ma0, Ma1, Mb0, Mb1;
  // Prologue order [S0, S1, M(0)x2, S2]: first iter's vmcnt(4) drains S0,S1,M0.
  STAGE(0);
  STAGE(1);
  Ma0 = mq0[0]; Ma1 = mq1[0];
  STAGE(2);

  for (int t2 = 0; t2 < 32; t2 += 2) {
    // step t2: consume Ma/buf[t2], prefetch M(t2+1) + Y(t2+3)
    Mb0 = mq0[(t2 + 1) & 31]; Mb1 = mq1[(t2 + 1) & 31];
    STAGE(t2 + 3);
    WAIT_VM4;            // drains S(t2), M(t2); keeps S(t2+1..3), M(t2+1)
    BARRIER; MEMBAR;     // ALL waves' S(t2) portions now in LDS
    COMPUTE(t2, Ma0, Ma1);
    // step t2+1
    Ma0 = mq0[(t2 + 2) & 31]; Ma1 = mq1[(t2 + 2) & 31];
    STAGE(t2 + 4);
    WAIT_VM4;
    BARRIER; MEMBAR;
    COMPUTE(t2 + 1, Mb0, Mb1);
  }
  asm volatile("s_waitcnt vmcnt(0)" ::: "memory");  // drain wrapped dummies

  // C partial write: dequant (x 1/16) -> bf16 plane ksp in ws.
  // C layout: col = lane&31, row = (reg&3) + 8*(reg>>2) + 4*(lane>>5).
#pragma unroll
  for (int mf = 0; mf < 2; ++mf)
#pragma unroll
    for (int nf = 0; nf < 2; ++nf) {
      const int col = ncol0 + (nf << 5) + l31;
#pragma unroll
      for (int r = 0; r < 16; ++r) {
        const int row = i0 + (w << 6) + (mf << 5) + (r & 3) + ((r >> 2) << 3) + (l5 << 2);
        Cp[((size_t)ksp * NN + row) * 512 + col] = f2bf((float)acc[mf][nf][r] * 0.0625f);
      }
    }
#undef BARRIER
#undef MEMBAR
#undef WAIT_VM4
#undef STAGE
#undef COMPUTE
}

// ---------------------------------------------------------------------------
// K3: epi (fused).  One 64-lane wave per (b,i); lane = fo.
// v = relu(S + [deg>0]*((Cp0+Cp1)/max(deg,1) + b_neigh)); LayerNorm; f32 out.
// ---------------------------------------------------------------------------
__global__ __launch_bounds__(256) void epi_kernel(
    const unsigned short* __restrict__ Cp, const float* __restrict__ degp,
    const unsigned short* __restrict__ Sbf, const float* __restrict__ bneigh,
    const float* __restrict__ gamma, const float* __restrict__ beta,
    float* __restrict__ out) {
  const int lane = threadIdx.x & 63;
  const int wid = (blockIdx.x << 2) + (threadIdx.x >> 6);
  const int b = wid >> 13;
  const int i = wid & (NN - 1);
  const float deg = degp[i] + degp[NN + i];
  const float rdeg = 1.0f / fmaxf(deg, 1.0f);
  const size_t cidx = (size_t)i * 512 + b * 64 + lane;
  const float c = bf2f(Cp[cidx]) + bf2f(Cp[(size_t)NN * 512 + cidx]);
  const float sv = bf2f(Sbf[((size_t)b * NN + i) * 64 + lane]);
  float v = sv + ((deg > 0.5f) ? (c * rdeg + bneigh[lane]) : 0.0f);
  v = fmaxf(v, 0.0f);
  float s1 = v, s2 = v * v;
#pragma unroll
  for (int m = 1; m < 64; m <<= 1) {
    s1 += __shfl_xor(s1, m);
    s2 += __shfl_xor(s2, m);
  }
  const float mu = s1 * 0.015625f;
  const float var = s2 * 0.015625f - mu * mu;
  const float o = (v - mu) * rsqrtf(var + 1e-5f) * gamma[lane] + beta[lane];
  out[((size_t)b * NN + i) * 64 + lane] = o;
}

extern "C" void kernel_launch(void* const* d_in, const int* in_sizes, int n_in,
                              void* d_out, int out_size, void* d_ws, size_t ws_size,
                              hipStream_t stream) {
  (void)in_sizes; (void)n_in; (void)out_size; (void)ws_size;
  const float* x      = (const float*)d_in[0];
  const int*   adj    = (const int*)d_in[1];
  const float* Wself  = (const float*)d_in[2];
  const float* bself  = (const float*)d_in[3];
  const float* Wneigh = (const float*)d_in[4];
  const float* bneigh = (const float*)d_in[5];
  const float* gamma  = (const float*)d_in[6];
  const float* beta   = (const float*)d_in[7];
  char* ws = (char*)d_ws;
  // ws layout (~37 MB):
  char*               Yq   = ws;                                     //  4 MB
  unsigned long long* mask = (unsigned long long*)(ws + 4194304);    //  8 MB
  unsigned short*     Sbf  = (unsigned short*)(ws + 12582912);       //  8 MB
  unsigned short*     Cp   = (unsigned short*)(ws + 20971520);       // 16.7 MB (2 planes)
  float*              degp = (float*)(ws + 37748736);                // 64 KB
  float*              out  = (float*)d_out;

  pack_kernel<<<dim3(4096), dim3(256), 0, stream>>>(adj, mask, degp);
  prep_kernel<<<dim3(1024), dim3(256), 0, stream>>>(x, Wself, bself, Wneigh, Yq, Sbf);
  gemm_kernel<<<dim3(256), dim3(512), 0, stream>>>((const i32x4*)mask, Yq, Cp);
  epi_kernel<<<dim3(16384), dim3(256), 0, stream>>>(Cp, degp, Sbf, bneigh, gamma, beta, out);
}

// Round 10
// 119.052 us; speedup vs baseline: 3.3269x; 1.0755x over previous
//
#include <hip/hip_runtime.h>

#define NN 8192

typedef __bf16 bf16x8 __attribute__((ext_vector_type(8)));
typedef float f32x4 __attribute__((ext_vector_type(4)));
typedef unsigned short u16x8 __attribute__((ext_vector_type(8)));
typedef int i32x4 __attribute__((ext_vector_type(4)));
typedef int i32x16 __attribute__((ext_vector_type(16)));

#define GLOBAL_AS __attribute__((address_space(1)))
#define LDS_AS __attribute__((address_space(3)))

__device__ __forceinline__ unsigned short f2bf(float f) {
  unsigned int u = __builtin_bit_cast(unsigned int, f);
  u += 0x7FFFu + ((u >> 16) & 1u);   // RNE
  return (unsigned short)(u >> 16);
}
__device__ __forceinline__ float bf2f(unsigned short b) {
  unsigned int u = ((unsigned int)b) << 16;
  return __builtin_bit_cast(float, u);
}

// 16 adjacency bits (low 16 of h) -> 16 i8 {0,1} via bit-spread multiply.
__device__ __forceinline__ i32x4 expA(unsigned int h) {
  i32x4 a;
  a[0] = (int)((((h      ) & 0xFu) * 0x204081u) & 0x01010101u);
  a[1] = (int)((((h >> 4 ) & 0xFu) * 0x204081u) & 0x01010101u);
  a[2] = (int)((((h >> 8 ) & 0xFu) * 0x204081u) & 0x01010101u);
  a[3] = (int)((((h >> 12) & 0xFu) * 0x204081u) & 0x01010101u);
  return a;
}

// ---------------------------------------------------------------------------
// K0: pack.  Streams adj (268 MB) ONCE, fully coalesced; emits the
// TRANSPOSED mask:  maskT2[P][row] : 16B = k-bits [P*128, P*128+128) of row
// (P = ksp*32 + t  ->  gemm step t reads 512B contiguous per instr), and
// degp[half][row].  Per wave: one (row, half); 16 x 1KB-contiguous loads ->
// nibbles -> 1KB LDS transpose -> u64 words -> paired 16B stores.
// XCD row-blocking (bid&7 owns rows [xcd*1024,+1024)) merges store lines.
// ---------------------------------------------------------------------------
__global__ __launch_bounds__(256) void pack_kernel(
    const int* __restrict__ adj, unsigned long long* __restrict__ maskT,
    float* __restrict__ degp) {
  __shared__ __align__(16) unsigned char xb[4][1024];
  const int lane = threadIdx.x & 63;
  const int wv = threadIdx.x >> 6;
  const int bid = blockIdx.x;
  const int row = ((bid & 7) << 10) + ((bid >> 3) << 1) + (wv >> 1);
  const int half = wv & 1;
  const int* src = adj + (size_t)row * NN + half * 4096;
  // elem e = c*256 + lane*4 + r  ->  word W = c*4 + (lane>>4), bit (lane&15)*4+r
  unsigned int nib[16];
#pragma unroll
  for (int c = 0; c < 16; ++c) {
    int4 v = *(const int4*)(src + c * 256 + lane * 4);
    nib[c] = (unsigned int)(v.x > 0)
           | ((unsigned int)(v.y > 0) << 1)
           | ((unsigned int)(v.z > 0) << 2)
           | ((unsigned int)(v.w > 0) << 3);
  }
  // transpose: byte addr c*64+lane  ==  word (c*4+(lane>>4)) * 16 + (lane&15)
#pragma unroll
  for (int c = 0; c < 16; ++c) xb[wv][c * 64 + lane] = (unsigned char)nib[c];
  __syncthreads();
  // lane j assembles word j from bytes [j*16, j*16+16)
  uint4 B = *(const uint4*)&xb[wv][lane * 16];
  unsigned int t0 = (B.x | (B.x >> 4)) & 0x00FF00FFu; t0 = (t0 | (t0 >> 8)) & 0xFFFFu;
  unsigned int t1 = (B.y | (B.y >> 4)) & 0x00FF00FFu; t1 = (t1 | (t1 >> 8)) & 0xFFFFu;
  unsigned int t2 = (B.z | (B.z >> 4)) & 0x00FF00FFu; t2 = (t2 | (t2 >> 8)) & 0xFFFFu;
  unsigned int t3 = (B.w | (B.w >> 4)) & 0x00FF00FFu; t3 = (t3 | (t3 >> 8)) & 0xFFFFu;
  unsigned long long word = (unsigned long long)(t0 | (t1 << 16))
                          | ((unsigned long long)(t2 | (t3 << 16)) << 32);
  // store: P = half*32 + (lane>>1), slot = lane&1  (lane pairs -> 16B)
  const size_t P = (size_t)((half << 5) + (lane >> 1));
  maskT[(P * NN + row) * 2 + (lane & 1)] = word;
  int deg = (int)__popcll(word);
#pragma unroll
  for (int m = 1; m < 64; m <<= 1) deg += __shfl_xor(deg, m);
  if (lane == 0) degp[half * NN + row] = (float)deg;
}

// ---------------------------------------------------------------------------
// K1: prep.  Per block: one batch b, 64 nodes.  Computes
//   Yq[(b*64+fo)][j] = i8( round(16 * x[b,j,:] @ W_neigh[:,fo]) )  (transposed)
//   Sbf[b,j,fo]      = bf16( x[b,j,:] @ W_self [:,fo] + b_self[fo] )
// ---------------------------------------------------------------------------
__global__ __launch_bounds__(256) void prep_kernel(
    const float* __restrict__ x, const float* __restrict__ Wself,
    const float* __restrict__ bself, const float* __restrict__ Wneigh,
    char* __restrict__ Yq, unsigned short* __restrict__ Sout) {
  __shared__ __align__(16) unsigned short xa[64 * 64];    // [j][k] swizzled
  __shared__ __align__(16) unsigned short bm[128 * 64];   // [n][k]; n<64: Wneigh, n>=64: Wself
  const int t = threadIdx.x;
  const int b = blockIdx.x >> 7;
  const int j0 = (blockIdx.x & 127) << 6;

  {
    const float* Wsel = (t < 128) ? Wneigh : Wself;
    const int tt = t & 127;
    const int k = tt >> 1;
    const int c0 = (tt & 1) << 5;
    const int nbase = (t < 128) ? 0 : 64;
    const float4* src = (const float4*)(Wsel + k * 64 + c0);
#pragma unroll
    for (int q = 0; q < 8; ++q) {
      float4 v = src[q];
      int n0 = nbase + c0 + q * 4;
      int n;
      n = n0 + 0; bm[n * 64 + (k ^ ((n & 7) << 3))] = f2bf(v.x);
      n = n0 + 1; bm[n * 64 + (k ^ ((n & 7) << 3))] = f2bf(v.y);
      n = n0 + 2; bm[n * 64 + (k ^ ((n & 7) << 3))] = f2bf(v.z);
      n = n0 + 3; bm[n * 64 + (k ^ ((n & 7) << 3))] = f2bf(v.w);
    }
  }
  {
    const int j = t >> 2, q = t & 3;
    const float* xrow = x + ((size_t)b * NN + j0 + j) * 64 + q * 16;
    float4 v0 = *(const float4*)(xrow + 0);
    float4 v1 = *(const float4*)(xrow + 4);
    float4 v2 = *(const float4*)(xrow + 8);
    float4 v3 = *(const float4*)(xrow + 12);
    u16x8 p0, p1;
    p0[0] = f2bf(v0.x); p0[1] = f2bf(v0.y); p0[2] = f2bf(v0.z); p0[3] = f2bf(v0.w);
    p0[4] = f2bf(v1.x); p0[5] = f2bf(v1.y); p0[6] = f2bf(v1.z); p0[7] = f2bf(v1.w);
    p1[0] = f2bf(v2.x); p1[1] = f2bf(v2.y); p1[2] = f2bf(v2.z); p1[3] = f2bf(v2.w);
    p1[4] = f2bf(v3.x); p1[5] = f2bf(v3.y); p1[6] = f2bf(v3.z); p1[7] = f2bf(v3.w);
    const int base = q * 16;
    const int sw = (j & 7) << 3;
    *(u16x8*)&xa[j * 64 + (base ^ sw)] = p0;
    *(u16x8*)&xa[j * 64 + ((base + 8) ^ sw)] = p1;
  }
  __syncthreads();

  const int lane = t & 63, w = t >> 6;
  const int rl = lane & 15, hi = lane >> 4;
  f32x4 acc[8];
#pragma unroll
  for (int i = 0; i < 8; ++i) acc[i] = (f32x4){0.f, 0.f, 0.f, 0.f};

#pragma unroll
  for (int ks = 0; ks < 2; ++ks) {
    const int r = w * 16 + rl;
    const int kel = ks * 32 + hi * 8;
    bf16x8 af = __builtin_bit_cast(bf16x8, *(u16x8*)&xa[r * 64 + (kel ^ ((r & 7) << 3))]);
#pragma unroll
    for (int nf = 0; nf < 8; ++nf) {
      const int n = nf * 16 + rl;
      bf16x8 bv = __builtin_bit_cast(bf16x8, *(u16x8*)&bm[n * 64 + (kel ^ ((n & 7) << 3))]);
      acc[nf] = __builtin_amdgcn_mfma_f32_16x16x32_bf16(af, bv, acc[nf], 0, 0, 0);
    }
  }
#pragma unroll
  for (int nf = 0; nf < 8; ++nf) {
    if (nf < 4) {
      const int n = nf * 16 + rl;             // global col = b*64+n
      unsigned int pkt = 0;
#pragma unroll
      for (int r = 0; r < 4; ++r) {
        float v = fminf(fmaxf(acc[nf][r] * 16.0f, -127.0f), 127.0f);
        int iv = __float2int_rn(v);
        pkt |= ((unsigned int)(iv & 0xFF)) << (r * 8);
      }
      *(unsigned int*)(Yq + (size_t)(b * 64 + n) * NN + j0 + w * 16 + hi * 4) = pkt;
    } else {
      const int fo = (nf - 4) * 16 + rl;
      const float bsv = bself[fo];
#pragma unroll
      for (int r = 0; r < 4; ++r) {
        const int jj = w * 16 + hi * 4 + r;
        Sout[((size_t)b * NN + j0 + jj) * 64 + fo] = f2bf(acc[nf][r] + bsv);
      }
    }
  }
}

// ---------------------------------------------------------------------------
// K2: big GEMM  C[i][n] = sum_j bit(i,j) * Yq[n][j] / 16,  n = b*64+fo.
// i8 MFMA; BM=512 (8 waves x 64 rows), BN=64, ksp=2 -> grid 256 (1 block/CU).
// K-step 128.  Y: 8-buffer LDS ring staged 3 ahead via global_load_lds.
// Mask: TRANSPOSED maskT2[P][row] -> per step one 512B-coalesced i32x4 load
// per row-frag (streamed once, L2-hit at the vmcnt wait; no line thrash).
// Per iter {LOADM(t+1); STAGE(t+3); s_waitcnt vmcnt(4); s_barrier}.
// C bf16 partials (2 ksp planes) -> ws (combined by epi).
// ---------------------------------------------------------------------------
__global__ __launch_bounds__(512, 1) void gemm_kernel(
    const i32x4* __restrict__ mask,     // maskT2: [128 P][8192 row] x 16B
    const char* __restrict__ Yq,        // [512][8192] i8
    unsigned short* __restrict__ Cp) {
  __shared__ __align__(16) char yL[8][8192];   // 64 KB ring
  const int tid = threadIdx.x;
  const int lane = tid & 63, w = tid >> 6;
  const int nid = ((blockIdx.x & 7) << 5) + (blockIdx.x >> 3);
  const int q = nid >> 4, mb = nid & 15;
  const int ksp = q >> 3, nb = q & 7;
  const int i0 = mb << 9;            // 512 rows
  const int kbase = ksp << 12;       // k offset (elems)
  const int ncol0 = nb << 6;         // 64 cols
  const int l31 = lane & 31, l5 = lane >> 5;
  const int hs16 = l5 << 4;

  // Y staging: wave w stages cols [w*8, w*8+8); src granule-swizzled, dest linear.
  const int cst = (w << 3) + (lane >> 3);
  const char* ysrc = Yq + (size_t)(ncol0 + cst) * NN + kbase
                     + (((lane & 7) ^ (cst & 7)) << 4);
  // mask (transposed): entry (P, row) at P*NN + row; P = ksp*32 + t.
  // Wave base: row = i0 + w*64 + l31 (mf=0) / +32 (mf=1).
  const i32x4* mqT = mask + ((size_t)(ksp << 5)) * NN + i0 + (w << 6) + l31;

  // B-read LDS byte offsets per [nf][s] (granule-swizzled)
  int boff[2][4];
#pragma unroll
  for (int nf = 0; nf < 2; ++nf)
#pragma unroll
    for (int s = 0; s < 4; ++s) {
      const int col = (nf << 5) + l31;
      const int g = (s << 1) + l5;
      boff[nf][s] = (col << 7) + ((g ^ (col & 7)) << 4);
    }

  i32x16 acc[2][2];
#pragma unroll
  for (int mf = 0; mf < 2; ++mf)
#pragma unroll
    for (int nf = 0; nf < 2; ++nf)
#pragma unroll
      for (int e = 0; e < 16; ++e) acc[mf][nf][e] = 0;

#define BARRIER  __builtin_amdgcn_s_barrier()
#define MEMBAR   asm volatile("" ::: "memory")
#define WAIT_VM4 asm volatile("s_waitcnt vmcnt(4)" ::: "memory")

#define STAGE(t)                                                              \
  __builtin_amdgcn_global_load_lds(                                           \
      (GLOBAL_AS void*)const_cast<char*>(ysrc + (size_t)((t) & 31) * 128),    \
      (LDS_AS void*)&yL[(t) & 7][w << 10], 16, 0, 0)

#define LOADM(M0, M1, t)                                                      \
  { M0 = mqT[(size_t)((t) & 31) * NN]; M1 = mqT[(size_t)((t) & 31) * NN + 32]; }

#define COMPUTE(t, M0, M1)                                                    \
  {                                                                           \
    const char* yb_ = &yL[(t) & 7][0];                                        \
    __builtin_amdgcn_s_setprio(1);                                            \
    _Pragma("unroll")                                                         \
    for (int s_ = 0; s_ < 4; ++s_) {                                          \
      i32x4 b0_ = *(const i32x4*)(yb_ + boff[0][s_]);                         \
      i32x4 b1_ = *(const i32x4*)(yb_ + boff[1][s_]);                         \
      unsigned int h0_ = (unsigned int)(M0)[s_] >> hs16;                      \
      unsigned int h1_ = (unsigned int)(M1)[s_] >> hs16;                      \
      i32x4 a0_ = expA(h0_);                                                  \
      i32x4 a1_ = expA(h1_);                                                  \
      acc[0][0] = __builtin_amdgcn_mfma_i32_32x32x32_i8(a0_, b0_, acc[0][0], 0, 0, 0); \
      acc[0][1] = __builtin_amdgcn_mfma_i32_32x32x32_i8(a0_, b1_, acc[0][1], 0, 0, 0); \
      acc[1][0] = __builtin_amdgcn_mfma_i32_32x32x32_i8(a1_, b0_, acc[1][0], 0, 0, 0); \
      acc[1][1] = __builtin_amdgcn_mfma_i32_32x32x32_i8(a1_, b1_, acc[1][1], 0, 0, 0); \
    }                                                                         \
    __builtin_amdgcn_s_setprio(0);                                            \
  }

  i32x4 Ma0, Ma1, Mb0, Mb1;
  // Prologue order [S0, S1, M(0)x2, S2]: first iter's vmcnt(4) drains S0,S1,M0.
  STAGE(0);
  STAGE(1);
  LOADM(Ma0, Ma1, 0);
  STAGE(2);

  for (int t2 = 0; t2 < 32; t2 += 2) {
    // step t2: consume Ma/buf[t2], prefetch M(t2+1) + Y(t2+3)
    LOADM(Mb0, Mb1, t2 + 1);
    STAGE(t2 + 3);
    WAIT_VM4;            // drains S(t2), M(t2); keeps S(t2+1..3), M(t2+1)
    BARRIER; MEMBAR;     // ALL waves' S(t2) portions now in LDS
    COMPUTE(t2, Ma0, Ma1);
    // step t2+1
    LOADM(Ma0, Ma1, t2 + 2);
    STAGE(t2 + 4);
    WAIT_VM4;
    BARRIER; MEMBAR;
    COMPUTE(t2 + 1, Mb0, Mb1);
  }
  asm volatile("s_waitcnt vmcnt(0)" ::: "memory");  // drain wrapped dummies

  // C partial write: dequant (x 1/16) -> bf16 plane ksp in ws.
  // C layout: col = lane&31, row = (reg&3) + 8*(reg>>2) + 4*(lane>>5).
#pragma unroll
  for (int mf = 0; mf < 2; ++mf)
#pragma unroll
    for (int nf = 0; nf < 2; ++nf) {
      const int col = ncol0 + (nf << 5) + l31;
#pragma unroll
      for (int r = 0; r < 16; ++r) {
        const int row = i0 + (w << 6) + (mf << 5) + (r & 3) + ((r >> 2) << 3) + (l5 << 2);
        Cp[((size_t)ksp * NN + row) * 512 + col] = f2bf((float)acc[mf][nf][r] * 0.0625f);
      }
    }
#undef BARRIER
#undef MEMBAR
#undef WAIT_VM4
#undef STAGE
#undef LOADM
#undef COMPUTE
}

// ---------------------------------------------------------------------------
// K3: epi (fused).  One 64-lane wave per (b,i); lane = fo.
// v = relu(S + [deg>0]*((Cp0+Cp1)/max(deg,1) + b_neigh)); LayerNorm; f32 out.
// ---------------------------------------------------------------------------
__global__ __launch_bounds__(256) void epi_kernel(
    const unsigned short* __restrict__ Cp, const float* __restrict__ degp,
    const unsigned short* __restrict__ Sbf, const float* __restrict__ bneigh,
    const float* __restrict__ gamma, const float* __restrict__ beta,
    float* __restrict__ out) {
  const int lane = threadIdx.x & 63;
  const int wid = (blockIdx.x << 2) + (threadIdx.x >> 6);
  const int b = wid >> 13;
  const int i = wid & (NN - 1);
  const float deg = degp[i] + degp[NN + i];
  const float rdeg = 1.0f / fmaxf(deg, 1.0f);
  const size_t cidx = (size_t)i * 512 + b * 64 + lane;
  const float c = bf2f(Cp[cidx]) + bf2f(Cp[(size_t)NN * 512 + cidx]);
  const float sv = bf2f(Sbf[((size_t)b * NN + i) * 64 + lane]);
  float v = sv + ((deg > 0.5f) ? (c * rdeg + bneigh[lane]) : 0.0f);
  v = fmaxf(v, 0.0f);
  float s1 = v, s2 = v * v;
#pragma unroll
  for (int m = 1; m < 64; m <<= 1) {
    s1 += __shfl_xor(s1, m);
    s2 += __shfl_xor(s2, m);
  }
  const float mu = s1 * 0.015625f;
  const float var = s2 * 0.015625f - mu * mu;
  const float o = (v - mu) * rsqrtf(var + 1e-5f) * gamma[lane] + beta[lane];
  out[((size_t)b * NN + i) * 64 + lane] = o;
}

extern "C" void kernel_launch(void* const* d_in, const int* in_sizes, int n_in,
                              void* d_out, int out_size, void* d_ws, size_t ws_size,
                              hipStream_t stream) {
  (void)in_sizes; (void)n_in; (void)out_size; (void)ws_size;
  const float* x      = (const float*)d_in[0];
  const int*   adj    = (const int*)d_in[1];
  const float* Wself  = (const float*)d_in[2];
  const float* bself  = (const float*)d_in[3];
  const float* Wneigh = (const float*)d_in[4];
  const float* bneigh = (const float*)d_in[5];
  const float* gamma  = (const float*)d_in[6];
  const float* beta   = (const float*)d_in[7];
  char* ws = (char*)d_ws;
  // ws layout (~37 MB):
  char*               Yq    = ws;                                    //  4 MB
  unsigned long long* maskT = (unsigned long long*)(ws + 4194304);   //  8 MB (transposed)
  unsigned short*     Sbf   = (unsigned short*)(ws + 12582912);      //  8 MB
  unsigned short*     Cp    = (unsigned short*)(ws + 20971520);      // 16.7 MB (2 planes)
  float*              degp  = (float*)(ws + 37748736);               // 64 KB
  float*              out   = (float*)d_out;

  pack_kernel<<<dim3(4096), dim3(256), 0, stream>>>(adj, maskT, degp);
  prep_kernel<<<dim3(1024), dim3(256), 0, stream>>>(x, Wself, bself, Wneigh, Yq, Sbf);
  gemm_kernel<<<dim3(256), dim3(512), 0, stream>>>((const i32x4*)maskT, Yq, Cp);
  epi_kernel<<<dim3(16384), dim3(256), 0, stream>>>(Cp, degp, Sbf, bneigh, gamma, beta, out);
}

// Round 11
// 118.913 us; speedup vs baseline: 3.3308x; 1.0012x over previous
//
#include <hip/hip_runtime.h>

#define NN 8192

typedef __bf16 bf16x8 __attribute__((ext_vector_type(8)));
typedef float f32x4 __attribute__((ext_vector_type(4)));
typedef unsigned short u16x8 __attribute__((ext_vector_type(8)));
typedef int i32x4 __attribute__((ext_vector_type(4)));
typedef int i32x16 __attribute__((ext_vector_type(16)));

#define GLOBAL_AS __attribute__((address_space(1)))
#define LDS_AS __attribute__((address_space(3)))

__device__ __forceinline__ unsigned short f2bf(float f) {
  unsigned int u = __builtin_bit_cast(unsigned int, f);
  u += 0x7FFFu + ((u >> 16) & 1u);   // RNE
  return (unsigned short)(u >> 16);
}
__device__ __forceinline__ float bf2f(unsigned short b) {
  unsigned int u = ((unsigned int)b) << 16;
  return __builtin_bit_cast(float, u);
}

// 16 adjacency bits (low 16 of h) -> 16 i8 {0,1} via bit-spread multiply.
__device__ __forceinline__ i32x4 expA(unsigned int h) {
  i32x4 a;
  a[0] = (int)((((h      ) & 0xFu) * 0x204081u) & 0x01010101u);
  a[1] = (int)((((h >> 4 ) & 0xFu) * 0x204081u) & 0x01010101u);
  a[2] = (int)((((h >> 8 ) & 0xFu) * 0x204081u) & 0x01010101u);
  a[3] = (int)((((h >> 12) & 0xFu) * 0x204081u) & 0x01010101u);
  return a;
}

// ---------------------------------------------------------------------------
// K0: packprep (fused).  Blocks [0,4096): pack adj -> transposed bitmask
// (coalesced stream, 268 MB once) + deg.  Blocks [4096,5120): prep
// (x @ W_neigh -> Yq i8 transposed;  x @ W_self + b_self -> Sbf).
// pack is HBM-bound, prep is MFMA-bound -> co-residency overlaps them.
// ---------------------------------------------------------------------------
__global__ __launch_bounds__(256) void packprep_kernel(
    const int* __restrict__ adj, unsigned long long* __restrict__ maskT,
    float* __restrict__ degp,
    const float* __restrict__ x, const float* __restrict__ Wself,
    const float* __restrict__ bself, const float* __restrict__ Wneigh,
    char* __restrict__ Yq, unsigned short* __restrict__ Sout) {
  __shared__ __align__(16) unsigned char xb[4][1024];     // pack: 4 KB
  __shared__ __align__(16) unsigned short xa[64 * 64];    // prep: 8 KB
  __shared__ __align__(16) unsigned short bm[128 * 64];   // prep: 16 KB

  if (blockIdx.x < 4096) {
    // ============================ pack ============================
    const int lane = threadIdx.x & 63;
    const int wv = threadIdx.x >> 6;
    const int bid = blockIdx.x;
    const int row = ((bid & 7) << 10) + ((bid >> 3) << 1) + (wv >> 1);
    const int half = wv & 1;
    const int* src = adj + (size_t)row * NN + half * 4096;
    unsigned int nib[16];
#pragma unroll
    for (int c = 0; c < 16; ++c) {
      int4 v = *(const int4*)(src + c * 256 + lane * 4);
      nib[c] = (unsigned int)(v.x > 0)
             | ((unsigned int)(v.y > 0) << 1)
             | ((unsigned int)(v.z > 0) << 2)
             | ((unsigned int)(v.w > 0) << 3);
    }
#pragma unroll
    for (int c = 0; c < 16; ++c) xb[wv][c * 64 + lane] = (unsigned char)nib[c];
    __syncthreads();
    uint4 B = *(const uint4*)&xb[wv][lane * 16];
    unsigned int t0 = (B.x | (B.x >> 4)) & 0x00FF00FFu; t0 = (t0 | (t0 >> 8)) & 0xFFFFu;
    unsigned int t1 = (B.y | (B.y >> 4)) & 0x00FF00FFu; t1 = (t1 | (t1 >> 8)) & 0xFFFFu;
    unsigned int t2 = (B.z | (B.z >> 4)) & 0x00FF00FFu; t2 = (t2 | (t2 >> 8)) & 0xFFFFu;
    unsigned int t3 = (B.w | (B.w >> 4)) & 0x00FF00FFu; t3 = (t3 | (t3 >> 8)) & 0xFFFFu;
    unsigned long long word = (unsigned long long)(t0 | (t1 << 16))
                            | ((unsigned long long)(t2 | (t3 << 16)) << 32);
    const size_t P = (size_t)((half << 5) + (lane >> 1));
    maskT[(P * NN + row) * 2 + (lane & 1)] = word;
    int deg = (int)__popcll(word);
#pragma unroll
    for (int m = 1; m < 64; m <<= 1) deg += __shfl_xor(deg, m);
    if (lane == 0) degp[half * NN + row] = (float)deg;
    return;
  }

  // ============================ prep ============================
  const int t = threadIdx.x;
  const int pb = blockIdx.x - 4096;
  const int b = pb >> 7;
  const int j0 = (pb & 127) << 6;

  {
    const float* Wsel = (t < 128) ? Wneigh : Wself;
    const int tt = t & 127;
    const int k = tt >> 1;
    const int c0 = (tt & 1) << 5;
    const int nbase = (t < 128) ? 0 : 64;
    const float4* src = (const float4*)(Wsel + k * 64 + c0);
#pragma unroll
    for (int q = 0; q < 8; ++q) {
      float4 v = src[q];
      int n0 = nbase + c0 + q * 4;
      int n;
      n = n0 + 0; bm[n * 64 + (k ^ ((n & 7) << 3))] = f2bf(v.x);
      n = n0 + 1; bm[n * 64 + (k ^ ((n & 7) << 3))] = f2bf(v.y);
      n = n0 + 2; bm[n * 64 + (k ^ ((n & 7) << 3))] = f2bf(v.z);
      n = n0 + 3; bm[n * 64 + (k ^ ((n & 7) << 3))] = f2bf(v.w);
    }
  }
  {
    const int j = t >> 2, q = t & 3;
    const float* xrow = x + ((size_t)b * NN + j0 + j) * 64 + q * 16;
    float4 v0 = *(const float4*)(xrow + 0);
    float4 v1 = *(const float4*)(xrow + 4);
    float4 v2 = *(const float4*)(xrow + 8);
    float4 v3 = *(const float4*)(xrow + 12);
    u16x8 p0, p1;
    p0[0] = f2bf(v0.x); p0[1] = f2bf(v0.y); p0[2] = f2bf(v0.z); p0[3] = f2bf(v0.w);
    p0[4] = f2bf(v1.x); p0[5] = f2bf(v1.y); p0[6] = f2bf(v1.z); p0[7] = f2bf(v1.w);
    p1[0] = f2bf(v2.x); p1[1] = f2bf(v2.y); p1[2] = f2bf(v2.z); p1[3] = f2bf(v2.w);
    p1[4] = f2bf(v3.x); p1[5] = f2bf(v3.y); p1[6] = f2bf(v3.z); p1[7] = f2bf(v3.w);
    const int base = q * 16;
    const int sw = (j & 7) << 3;
    *(u16x8*)&xa[j * 64 + (base ^ sw)] = p0;
    *(u16x8*)&xa[j * 64 + ((base + 8) ^ sw)] = p1;
  }
  __syncthreads();

  const int lane = t & 63, w = t >> 6;
  const int rl = lane & 15, hi = lane >> 4;
  f32x4 acc[8];
#pragma unroll
  for (int i = 0; i < 8; ++i) acc[i] = (f32x4){0.f, 0.f, 0.f, 0.f};

#pragma unroll
  for (int ks = 0; ks < 2; ++ks) {
    const int r = w * 16 + rl;
    const int kel = ks * 32 + hi * 8;
    bf16x8 af = __builtin_bit_cast(bf16x8, *(u16x8*)&xa[r * 64 + (kel ^ ((r & 7) << 3))]);
#pragma unroll
    for (int nf = 0; nf < 8; ++nf) {
      const int n = nf * 16 + rl;
      bf16x8 bv = __builtin_bit_cast(bf16x8, *(u16x8*)&bm[n * 64 + (kel ^ ((n & 7) << 3))]);
      acc[nf] = __builtin_amdgcn_mfma_f32_16x16x32_bf16(af, bv, acc[nf], 0, 0, 0);
    }
  }
#pragma unroll
  for (int nf = 0; nf < 8; ++nf) {
    if (nf < 4) {
      const int n = nf * 16 + rl;             // global col = b*64+n
      unsigned int pkt = 0;
#pragma unroll
      for (int r = 0; r < 4; ++r) {
        float v = fminf(fmaxf(acc[nf][r] * 16.0f, -127.0f), 127.0f);
        int iv = __float2int_rn(v);
        pkt |= ((unsigned int)(iv & 0xFF)) << (r * 8);
      }
      *(unsigned int*)(Yq + (size_t)(b * 64 + n) * NN + j0 + w * 16 + hi * 4) = pkt;
    } else {
      const int fo = (nf - 4) * 16 + rl;
      const float bsv = bself[fo];
#pragma unroll
      for (int r = 0; r < 4; ++r) {
        const int jj = w * 16 + hi * 4 + r;
        Sout[((size_t)b * NN + j0 + jj) * 64 + fo] = f2bf(acc[nf][r] + bsv);
      }
    }
  }
}

// ---------------------------------------------------------------------------
// K2: big GEMM  C[i][n] = sum_j bit(i,j) * Yq[n][j] / 16,  n = b*64+fo.
// i8 MFMA; BM=256 (4 waves x 64 rows), BN=64, ksp=2 ->
// grid = 32mb x 8nb x 2ksp = 512 blocks = 2 BLOCKS/CU (64 KB ring each,
// 128 KB total): sibling blocks cover each other's barrier drains (R2's
// proven lever, lost in the R6 restructure).  K-step 128; Y staged 3 ahead
// (2 x global_load_lds per wave per step); mask transposed, coalesced,
// register double-buffered.  Per iter {LOADM(t+1) x2; STAGE(t+3) x2;
// s_waitcnt vmcnt(6); s_barrier}: drains S(t+1),M(t), keeps 6 in flight.
// ---------------------------------------------------------------------------
__global__ __launch_bounds__(256, 2) void gemm_kernel(
    const i32x4* __restrict__ mask,     // maskT2: [128 P][8192 row] x 16B
    const char* __restrict__ Yq,        // [512][8192] i8
    unsigned short* __restrict__ Cp) {
  __shared__ __align__(16) char yL[8][8192];   // 64 KB ring
  const int tid = threadIdx.x;
  const int lane = tid & 63, w = tid >> 6;     // w = 0..3
  const int nid = ((blockIdx.x & 7) << 6) + (blockIdx.x >> 3);
  const int ksp = nid >> 8;
  const int nb = (nid >> 5) & 7;
  const int mb = nid & 31;
  const int i0 = mb << 8;            // 256 rows
  const int kbase = ksp << 12;       // k offset (elems)
  const int ncol0 = nb << 6;         // 64 cols
  const int l31 = lane & 31, l5 = lane >> 5;
  const int hs16 = l5 << 4;

  // Y staging: wave w stages cols [w*16, w*16+16) as 2 loads of 8 cols.
  const int cst = (w << 4) + (lane >> 3);      // load0 col; load1 = +8
  const char* ysrc = Yq + (size_t)(ncol0 + cst) * NN + kbase
                     + (((lane & 7) ^ (cst & 7)) << 4);
  // mask (transposed): entry (P, row) at P*NN + row; P = ksp*32 + t.
  const i32x4* mqT = mask + ((size_t)(ksp << 5)) * NN + i0 + (w << 6) + l31;

  // B-read LDS byte offsets per [nf][s] (granule-swizzled)
  int boff[2][4];
#pragma unroll
  for (int nf = 0; nf < 2; ++nf)
#pragma unroll
    for (int s = 0; s < 4; ++s) {
      const int col = (nf << 5) + l31;
      const int g = (s << 1) + l5;
      boff[nf][s] = (col << 7) + ((g ^ (col & 7)) << 4);
    }

  i32x16 acc[2][2];
#pragma unroll
  for (int mf = 0; mf < 2; ++mf)
#pragma unroll
    for (int nf = 0; nf < 2; ++nf)
#pragma unroll
      for (int e = 0; e < 16; ++e) acc[mf][nf][e] = 0;

#define BARRIER  __builtin_amdgcn_s_barrier()
#define MEMBAR   asm volatile("" ::: "memory")
#define WAIT_VM6 asm volatile("s_waitcnt vmcnt(6)" ::: "memory")

#define STAGE(t)                                                              \
  {                                                                           \
    __builtin_amdgcn_global_load_lds(                                         \
        (GLOBAL_AS void*)const_cast<char*>(ysrc + (size_t)((t) & 31) * 128),  \
        (LDS_AS void*)&yL[(t) & 7][w << 11], 16, 0, 0);                       \
    __builtin_amdgcn_global_load_lds(                                         \
        (GLOBAL_AS void*)const_cast<char*>(ysrc + (size_t)8 * NN              \
                                           + (size_t)((t) & 31) * 128),       \
        (LDS_AS void*)&yL[(t) & 7][(w << 11) + 1024], 16, 0, 0);              \
  }

#define LOADM(M0, M1, t)                                                      \
  { M0 = mqT[(size_t)((t) & 31) * NN]; M1 = mqT[(size_t)((t) & 31) * NN + 32]; }

#define COMPUTE(t, M0, M1)                                                    \
  {                                                                           \
    const char* yb_ = &yL[(t) & 7][0];                                        \
    __builtin_amdgcn_s_setprio(1);                                            \
    _Pragma("unroll")                                                         \
    for (int s_ = 0; s_ < 4; ++s_) {                                          \
      i32x4 b0_ = *(const i32x4*)(yb_ + boff[0][s_]);                         \
      i32x4 b1_ = *(const i32x4*)(yb_ + boff[1][s_]);                         \
      unsigned int h0_ = (unsigned int)(M0)[s_] >> hs16;                      \
      unsigned int h1_ = (unsigned int)(M1)[s_] >> hs16;                      \
      i32x4 a0_ = expA(h0_);                                                  \
      i32x4 a1_ = expA(h1_);                                                  \
      acc[0][0] = __builtin_amdgcn_mfma_i32_32x32x32_i8(a0_, b0_, acc[0][0], 0, 0, 0); \
      acc[0][1] = __builtin_amdgcn_mfma_i32_32x32x32_i8(a0_, b1_, acc[0][1], 0, 0, 0); \
      acc[1][0] = __builtin_amdgcn_mfma_i32_32x32x32_i8(a1_, b0_, acc[1][0], 0, 0, 0); \
      acc[1][1] = __builtin_amdgcn_mfma_i32_32x32x32_i8(a1_, b1_, acc[1][1], 0, 0, 0); \
    }                                                                         \
    __builtin_amdgcn_s_setprio(0);                                            \
  }

  i32x4 Ma0, Ma1, Mb0, Mb1;
  // Prologue: S(0)2, S(1)2, S(2)2, M(0)2 in flight.
  STAGE(0);
  STAGE(1);
  STAGE(2);
  LOADM(Ma0, Ma1, 0);

  for (int t2 = 0; t2 < 32; t2 += 2) {
    // step t2: consume Ma/buf[t2]
    LOADM(Mb0, Mb1, t2 + 1);
    STAGE(t2 + 3);
    WAIT_VM6;            // drains S(t2), M(t2) (and older); keeps 6 newest
    BARRIER; MEMBAR;     // ALL waves' S(t2) portions now in LDS
    COMPUTE(t2, Ma0, Ma1);
    // step t2+1
    LOADM(Ma0, Ma1, t2 + 2);
    STAGE(t2 + 4);
    WAIT_VM6;
    BARRIER; MEMBAR;
    COMPUTE(t2 + 1, Mb0, Mb1);
  }
  asm volatile("s_waitcnt vmcnt(0)" ::: "memory");  // drain wrapped dummies

  // C partial write: dequant (x 1/16) -> bf16 plane ksp in ws.
  // C layout: col = lane&31, row = (reg&3) + 8*(reg>>2) + 4*(lane>>5).
#pragma unroll
  for (int mf = 0; mf < 2; ++mf)
#pragma unroll
    for (int nf = 0; nf < 2; ++nf) {
      const int col = ncol0 + (nf << 5) + l31;
#pragma unroll
      for (int r = 0; r < 16; ++r) {
        const int row = i0 + (w << 6) + (mf << 5) + (r & 3) + ((r >> 2) << 3) + (l5 << 2);
        Cp[((size_t)ksp * NN + row) * 512 + col] = f2bf((float)acc[mf][nf][r] * 0.0625f);
      }
    }
#undef BARRIER
#undef MEMBAR
#undef WAIT_VM6
#undef STAGE
#undef LOADM
#undef COMPUTE
}

// ---------------------------------------------------------------------------
// K3: epi (fused).  One 64-lane wave per (b,i); lane = fo.
// v = relu(S + [deg>0]*((Cp0+Cp1)/max(deg,1) + b_neigh)); LayerNorm; f32 out.
// ---------------------------------------------------------------------------
__global__ __launch_bounds__(256) void epi_kernel(
    const unsigned short* __restrict__ Cp, const float* __restrict__ degp,
    const unsigned short* __restrict__ Sbf, const float* __restrict__ bneigh,
    const float* __restrict__ gamma, const float* __restrict__ beta,
    float* __restrict__ out) {
  const int lane = threadIdx.x & 63;
  const int wid = (blockIdx.x << 2) + (threadIdx.x >> 6);
  const int b = wid >> 13;
  const int i = wid & (NN - 1);
  const float deg = degp[i] + degp[NN + i];
  const float rdeg = 1.0f / fmaxf(deg, 1.0f);
  const size_t cidx = (size_t)i * 512 + b * 64 + lane;
  const float c = bf2f(Cp[cidx]) + bf2f(Cp[(size_t)NN * 512 + cidx]);
  const float sv = bf2f(Sbf[((size_t)b * NN + i) * 64 + lane]);
  float v = sv + ((deg > 0.5f) ? (c * rdeg + bneigh[lane]) : 0.0f);
  v = fmaxf(v, 0.0f);
  float s1 = v, s2 = v * v;
#pragma unroll
  for (int m = 1; m < 64; m <<= 1) {
    s1 += __shfl_xor(s1, m);
    s2 += __shfl_xor(s2, m);
  }
  const float mu = s1 * 0.015625f;
  const float var = s2 * 0.015625f - mu * mu;
  const float o = (v - mu) * rsqrtf(var + 1e-5f) * gamma[lane] + beta[lane];
  out[((size_t)b * NN + i) * 64 + lane] = o;
}

extern "C" void kernel_launch(void* const* d_in, const int* in_sizes, int n_in,
                              void* d_out, int out_size, void* d_ws, size_t ws_size,
                              hipStream_t stream) {
  (void)in_sizes; (void)n_in; (void)out_size; (void)ws_size;
  const float* x      = (const float*)d_in[0];
  const int*   adj    = (const int*)d_in[1];
  const float* Wself  = (const float*)d_in[2];
  const float* bself  = (const float*)d_in[3];
  const float* Wneigh = (const float*)d_in[4];
  const float* bneigh = (const float*)d_in[5];
  const float* gamma  = (const float*)d_in[6];
  const float* beta   = (const float*)d_in[7];
  char* ws = (char*)d_ws;
  // ws layout (~37 MB):
  char*               Yq    = ws;                                    //  4 MB
  unsigned long long* maskT = (unsigned long long*)(ws + 4194304);   //  8 MB (transposed)
  unsigned short*     Sbf   = (unsigned short*)(ws + 12582912);      //  8 MB
  unsigned short*     Cp    = (unsigned short*)(ws + 20971520);      // 16.7 MB (2 planes)
  float*              degp  = (float*)(ws + 37748736);               // 64 KB
  float*              out   = (float*)d_out;

  packprep_kernel<<<dim3(5120), dim3(256), 0, stream>>>(
      adj, maskT, degp, x, Wself, bself, Wneigh, Yq, Sbf);
  gemm_kernel<<<dim3(512), dim3(256), 0, stream>>>((const i32x4*)maskT, Yq, Cp);
  epi_kernel<<<dim3(16384), dim3(256), 0, stream>>>(Cp, degp, Sbf, bneigh, gamma, beta, out);
}